// Round 1
// baseline (4556.316 us; speedup 1.0000x reference)
//
#include <hip/hip_runtime.h>
#include <math.h>
#include <stdint.h>

#define DD 1024
#define EE 8
#define FF 4096
#define CAPV 2048
#define TT 8192
#define LIST_STRIDE 4096   // per-expert entry capacity (2*CAP)
#define CHUNK 2048         // FFN row-chunk through H workspace

// ---------------- gating: logits, softmax, top-2, aux partial sums ----------
__global__ __launch_bounds__(256) void moe_gate_kernel(
    const float* __restrict__ x, const float* __restrict__ gw,
    int* __restrict__ e1o, int* __restrict__ e2o,
    float* __restrict__ g1o, float* __restrict__ g2o,
    float* __restrict__ sums)
{
    __shared__ float sgw[EE][DD];          // 32 KB
    __shared__ float wp[4][18];
    for (int i = threadIdx.x; i < EE * DD; i += 256) sgw[i >> 10][i & 1023] = gw[i];
    __syncthreads();

    const int wave = threadIdx.x >> 6, lane = threadIdx.x & 63;
    const int gwave = blockIdx.x * 4 + wave;
    const int nwaves = gridDim.x * 4;

    float pa_acc = 0.f, z_acc = 0.f;
    float P_acc[EE] = {0}, p6_acc[EE] = {0};

    for (int t = gwave; t < TT; t += nwaves) {
        float acc[EE] = {0};
        const float* xr = x + (size_t)t * DD;
        #pragma unroll
        for (int i = 0; i < DD / 64; ++i) {
            const float xv = xr[lane + 64 * i];
            #pragma unroll
            for (int e = 0; e < EE; ++e) acc[e] += xv * sgw[e][lane + 64 * i];
        }
        #pragma unroll
        for (int e = 0; e < EE; ++e) {
            float v = acc[e];
            #pragma unroll
            for (int off = 32; off > 0; off >>= 1) v += __shfl_xor(v, off, 64);
            acc[e] = v;                     // all lanes hold the logit
        }
        if (lane == 0) {
            float mx = acc[0];
            #pragma unroll
            for (int e = 1; e < EE; ++e) mx = fmaxf(mx, acc[e]);
            float pr[EE], p6[EE], se = 0.f, s6 = 0.f;
            #pragma unroll
            for (int e = 0; e < EE; ++e) {
                pr[e] = __expf(acc[e] - mx); se += pr[e];
                p6[e] = __expf((acc[e] - mx) * (1.0f / 1.66f)); s6 += p6[e];
            }
            const float lse = mx + __logf(se);
            z_acc += lse * lse;
            const float ise = 1.f / se, is6 = 1.f / s6;
            #pragma unroll
            for (int e = 0; e < EE; ++e) {
                pr[e] *= ise; p6[e] *= is6;
                P_acc[e] += pr[e]; p6_acc[e] += p6[e];
                pa_acc += p6[e] * (1.f - p6[e]);
            }
            int a = 0;
            #pragma unroll
            for (int e = 1; e < EE; ++e) if (pr[e] > pr[a]) a = e;
            int b = (a == 0) ? 1 : 0;
            #pragma unroll
            for (int e = 0; e < EE; ++e) if (e != a && pr[e] > pr[b]) b = e;
            const float ga = pr[a], gb = pr[b], idn = 1.f / (ga + gb);
            e1o[t] = a; e2o[t] = b;
            g1o[t] = ga * idn; g2o[t] = gb * idn;
        }
    }
    if (lane == 0) {
        wp[wave][0] = pa_acc; wp[wave][1] = z_acc;
        #pragma unroll
        for (int e = 0; e < EE; ++e) { wp[wave][2 + e] = P_acc[e]; wp[wave][10 + e] = p6_acc[e]; }
    }
    __syncthreads();
    if (threadIdx.x < 18) {
        const float s = wp[0][threadIdx.x] + wp[1][threadIdx.x] + wp[2][threadIdx.x] + wp[3][threadIdx.x];
        atomicAdd(&sums[threadIdx.x], s);
    }
}

// ---------------- ordered capacity scan + entry-list build ------------------
__device__ __forceinline__ int fld8(unsigned long long lo, unsigned long long hi, int e) {
    return (int)(((e < 4) ? (lo >> (16 * e)) : (hi >> (16 * (e - 4)))) & 0xFFFFull);
}

__global__ __launch_bounds__(256) void moe_scan_kernel(
    const int* __restrict__ e1i, const int* __restrict__ e2i,
    const float* __restrict__ g1i, const float* __restrict__ g2i,
    const float* __restrict__ rnd,
    int* __restrict__ etok, float* __restrict__ ew,
    int* __restrict__ cnt, float* __restrict__ imp, int* __restrict__ fcnt)
{
    __shared__ unsigned long long slo1[256], shi1[256], slo2[256], shi2[256];
    __shared__ int base1[EE], base2[EE], lcnt[EE], lfc[EE];
    __shared__ float limp[EE];
    const int tid = threadIdx.x;
    if (tid < EE) { base1[tid] = 0; base2[tid] = 0; lcnt[tid] = 0; lfc[tid] = 0; limp[tid] = 0.f; }
    __syncthreads();

    for (int c = 0; c < TT / 256; ++c) {
        const int t = c * 256 + tid;
        const int a1 = e1i[t], a2 = e2i[t];
        slo1[tid] = (a1 < 4) ? (1ull << (16 * a1)) : 0ull;
        shi1[tid] = (a1 >= 4) ? (1ull << (16 * (a1 - 4))) : 0ull;
        slo2[tid] = (a2 < 4) ? (1ull << (16 * a2)) : 0ull;
        shi2[tid] = (a2 >= 4) ? (1ull << (16 * (a2 - 4))) : 0ull;
        __syncthreads();
        for (int off = 1; off < 256; off <<= 1) {
            unsigned long long v1l = 0, v1h = 0, v2l = 0, v2h = 0;
            if (tid >= off) { v1l = slo1[tid - off]; v1h = shi1[tid - off];
                              v2l = slo2[tid - off]; v2h = shi2[tid - off]; }
            __syncthreads();
            slo1[tid] += v1l; shi1[tid] += v1h; slo2[tid] += v2l; shi2[tid] += v2h;
            __syncthreads();
        }
        const int pos1 = base1[a1] + fld8(slo1[tid], shi1[tid], a1) - 1;
        const int pos2 = base2[a2] + fld8(slo2[tid], shi2[tid], a2) - 1;
        const float gg1 = g1i[t], gg2 = g2i[t];
        const bool m1 = (pos1 < CAPV);
        const bool m2 = (pos2 < CAPV) && (rnd[t] < 2.f * gg2);
        atomicAdd(&lfc[a1], 1);
        if (m1) {
            const int idx = atomicAdd(&lcnt[a1], 1);
            etok[a1 * LIST_STRIDE + idx] = t; ew[a1 * LIST_STRIDE + idx] = gg1;
            atomicAdd(&limp[a1], gg1);
        }
        if (m2) {
            const int idx = atomicAdd(&lcnt[a2], 1);
            etok[a2 * LIST_STRIDE + idx] = t; ew[a2 * LIST_STRIDE + idx] = gg2;
            atomicAdd(&limp[a2], gg2);
        }
        __syncthreads();
        if (tid < EE) {
            base1[tid] += fld8(slo1[255], shi1[255], tid);
            base2[tid] += fld8(slo2[255], shi2[255], tid);
        }
        __syncthreads();
    }
    if (tid < EE) { cnt[tid] = lcnt[tid]; imp[tid] = limp[tid]; fcnt[tid] = lfc[tid]; }
}

// ---------------- aux scalar ------------------------------------------------
__global__ void moe_aux_kernel(const float* __restrict__ sums, const float* __restrict__ imp,
                               const int* __restrict__ fcnt, float* __restrict__ out_aux)
{
    if (threadIdx.x != 0 || blockIdx.x != 0) return;
    const float invT = 1.f / (float)TT;
    const float pa = sums[0] / ((float)TT * (float)EE);
    float pb = 0.f, load = 0.f, msum = 0.f;
    for (int e = 0; e < EE; ++e) {
        const float pm = sums[10 + e] * invT;
        pb += pm * (1.f - pm);
        load += ((float)fcnt[e] * invT) * (sums[2 + e] * invT);
        msum += imp[e];
    }
    pb = 1.f / (float)EE - pb / (float)EE;
    const float penalty = 0.01f * (pa + pb);
    const float z_loss = 0.001f * sums[1] * invT;
    const float load_loss = 0.01f * (float)EE * load;
    const float mean = msum / (float)EE;
    float var = 0.f;
    for (int e = 0; e < EE; ++e) { const float d = imp[e] - mean; var += d * d; }
    var /= (float)EE;
    const float imp_loss = 0.01f * var / (mean * mean);
    *out_aux = penalty + z_loss + load_loss + imp_loss;
}

// ---------------- FFN pass 1: H = gelu(Xg @ W1 + b1)  (M=CHUNK,N=FF,K=D) ----
#define BM 64
#define BN 64
#define BK 16

__global__ __launch_bounds__(256) void moe_ffn1_kernel(
    const float* __restrict__ x, const float* __restrict__ w1,
    const float* __restrict__ b1, const int* __restrict__ etok,
    const int* __restrict__ cnt, float* __restrict__ H, int e, int cb)
{
    const int ce = cnt[e];
    const int m0 = blockIdx.x * BM;
    if (cb + m0 >= ce) return;
    const int n0 = blockIdx.y * BN;
    const int tid = threadIdx.x;

    __shared__ float As[BK][BM + 4];
    __shared__ float Bs[BK][BN + 4];
    __shared__ int stok[BM];
    if (tid < BM) {
        const int gr = cb + m0 + tid;
        stok[tid] = (gr < ce) ? etok[e * LIST_STRIDE + gr] : -1;
    }
    __syncthreads();

    const float* W = w1 + (size_t)e * DD * FF;
    const int arow = tid >> 2, akk = (tid & 3) * 4;
    const int tokA = stok[arow];
    const float* aptr = (tokA >= 0) ? (x + (size_t)tokA * DD + akk) : nullptr;
    const int bkk = tid >> 4, bn = (tid & 15) * 4;
    const int tx = tid & 15, ty = tid >> 4;

    float acc[4][4] = {};
    for (int k0 = 0; k0 < DD; k0 += BK) {
        float4 av = make_float4(0.f, 0.f, 0.f, 0.f);
        if (aptr) av = *(const float4*)(aptr + k0);
        const float4 bv = *(const float4*)(W + (size_t)(k0 + bkk) * FF + n0 + bn);
        __syncthreads();
        As[akk + 0][arow] = av.x; As[akk + 1][arow] = av.y;
        As[akk + 2][arow] = av.z; As[akk + 3][arow] = av.w;
        *(float4*)&Bs[bkk][bn] = bv;
        __syncthreads();
        #pragma unroll
        for (int kk = 0; kk < BK; ++kk) {
            const float4 a4 = *(const float4*)&As[kk][ty * 4];
            const float4 b4 = *(const float4*)&Bs[kk][tx * 4];
            const float a[4] = {a4.x, a4.y, a4.z, a4.w};
            const float b[4] = {b4.x, b4.y, b4.z, b4.w};
            #pragma unroll
            for (int i = 0; i < 4; ++i)
                #pragma unroll
                for (int j = 0; j < 4; ++j)
                    acc[i][j] = fmaf(a[i], b[j], acc[i][j]);
        }
    }
    const float* b1e = b1 + (size_t)e * FF;
    #pragma unroll
    for (int i = 0; i < 4; ++i) {
        const int m = m0 + ty * 4 + i;
        float* hrow = H + (size_t)m * FF + n0 + tx * 4;
        #pragma unroll
        for (int j = 0; j < 4; ++j) {
            const float v = acc[i][j] + b1e[n0 + tx * 4 + j];
            const float c = 0.7978845608028654f * (v + 0.044715f * v * v * v);
            hrow[j] = 0.5f * v * (1.0f + tanhf(c));
        }
    }
}

// ---------------- FFN pass 2: y += w * (H @ W2 + b2)  (M=CHUNK,N=D,K=FF) ----
__global__ __launch_bounds__(256) void moe_ffn2_kernel(
    const float* __restrict__ H, const float* __restrict__ w2,
    const float* __restrict__ b2, const int* __restrict__ etok,
    const float* __restrict__ ew, const int* __restrict__ cnt,
    float* __restrict__ y, int e, int cb)
{
    const int ce = cnt[e];
    const int m0 = blockIdx.x * BM;
    if (cb + m0 >= ce) return;
    const int n0 = blockIdx.y * BN;
    const int tid = threadIdx.x;

    __shared__ float As[BK][BM + 4];
    __shared__ float Bs[BK][BN + 4];

    const float* W = w2 + (size_t)e * FF * DD;
    const int arow = tid >> 2, akk = (tid & 3) * 4;
    const float* aptr = H + (size_t)(m0 + arow) * FF + akk;
    const int bkk = tid >> 4, bn = (tid & 15) * 4;
    const int tx = tid & 15, ty = tid >> 4;

    float acc[4][4] = {};
    for (int k0 = 0; k0 < FF; k0 += BK) {
        const float4 av = *(const float4*)(aptr + k0);
        const float4 bv = *(const float4*)(W + (size_t)(k0 + bkk) * DD + n0 + bn);
        __syncthreads();
        As[akk + 0][arow] = av.x; As[akk + 1][arow] = av.y;
        As[akk + 2][arow] = av.z; As[akk + 3][arow] = av.w;
        *(float4*)&Bs[bkk][bn] = bv;
        __syncthreads();
        #pragma unroll
        for (int kk = 0; kk < BK; ++kk) {
            const float4 a4 = *(const float4*)&As[kk][ty * 4];
            const float4 b4 = *(const float4*)&Bs[kk][tx * 4];
            const float a[4] = {a4.x, a4.y, a4.z, a4.w};
            const float b[4] = {b4.x, b4.y, b4.z, b4.w};
            #pragma unroll
            for (int i = 0; i < 4; ++i)
                #pragma unroll
                for (int j = 0; j < 4; ++j)
                    acc[i][j] = fmaf(a[i], b[j], acc[i][j]);
        }
    }
    const float* b2e = b2 + (size_t)e * DD;
    #pragma unroll
    for (int i = 0; i < 4; ++i) {
        const int gr = cb + m0 + ty * 4 + i;
        if (gr < ce) {
            const int tok = etok[e * LIST_STRIDE + gr];
            const float w = ew[e * LIST_STRIDE + gr];
            #pragma unroll
            for (int j = 0; j < 4; ++j) {
                const int n = n0 + tx * 4 + j;
                atomicAdd(&y[(size_t)tok * DD + n], w * (acc[i][j] + b2e[n]));
            }
        }
    }
}

// ---------------- launch ----------------------------------------------------
extern "C" void kernel_launch(void* const* d_in, const int* in_sizes, int n_in,
                              void* d_out, int out_size, void* d_ws, size_t ws_size,
                              hipStream_t stream) {
    const float* x   = (const float*)d_in[0];
    const float* gw  = (const float*)d_in[1];
    const float* w1  = (const float*)d_in[2];
    const float* b1  = (const float*)d_in[3];
    const float* w2  = (const float*)d_in[4];
    const float* b2  = (const float*)d_in[5];
    const float* rnd = (const float*)d_in[6];
    float* out = (float*)d_out;

    char* p = (char*)d_ws;
    float* sums = (float*)p;                 // 18 floats used
    float* imp  = (float*)(p + 128);         // 8 floats
    int*   fcnt = (int*)(p + 192);           // 8 ints
    int*   cnt  = (int*)(p + 256);           // 8 ints
    p += 512;
    int*   e1v = (int*)p;   p += TT * 4;
    int*   e2v = (int*)p;   p += TT * 4;
    float* g1v = (float*)p; p += TT * 4;
    float* g2v = (float*)p; p += TT * 4;
    int*   etok = (int*)p;  p += EE * LIST_STRIDE * 4;
    float* ewv  = (float*)p; p += EE * LIST_STRIDE * 4;
    uintptr_t q = (((uintptr_t)p) + 255) & ~(uintptr_t)255;
    float* H = (float*)q;                    // CHUNK x FF fp32 = 32 MB

    hipMemsetAsync(sums, 0, 128, stream);
    hipMemsetAsync(d_out, 0, (size_t)TT * DD * sizeof(float), stream);

    moe_gate_kernel<<<128, 256, 0, stream>>>(x, gw, e1v, e2v, g1v, g2v, sums);
    moe_scan_kernel<<<1, 256, 0, stream>>>(e1v, e2v, g1v, g2v, rnd, etok, ewv, cnt, imp, fcnt);
    moe_aux_kernel<<<1, 64, 0, stream>>>(sums, imp, fcnt, out + (size_t)TT * DD);

    for (int e = 0; e < EE; ++e) {
        for (int cb = 0; cb < 2 * CAPV; cb += CHUNK) {
            moe_ffn1_kernel<<<dim3(CHUNK / BM, FF / BN), 256, 0, stream>>>(x, w1, b1, etok, cnt, H, e, cb);
            moe_ffn2_kernel<<<dim3(CHUNK / BM, DD / BN), 256, 0, stream>>>(H, w2, b2, etok, ewv, cnt, out, e, cb);
        }
    }
}

// Round 2
// 1456.511 us; speedup vs baseline: 3.1282x; 3.1282x over previous
//
#include <hip/hip_runtime.h>
#include <math.h>
#include <stdint.h>

#define DD 1024
#define EE 8
#define FF 4096
#define CAPV 2048
#define TT 8192
#define LIST_STRIDE 4096   // per-expert entry capacity (2*CAP)

typedef __bf16 bf16x8 __attribute__((ext_vector_type(8)));
typedef float floatx4 __attribute__((ext_vector_type(4)));

typedef __attribute__((address_space(3))) unsigned int as3_uint;
typedef __attribute__((address_space(1))) const unsigned int as1_uint;

__device__ __forceinline__ void gl_lds16(const void* g, void* l) {
    __builtin_amdgcn_global_load_lds((as1_uint*)g, (as3_uint*)l, 16, 0, 0);
}

__device__ __forceinline__ unsigned short f2bf(float f) {
    union { float f; unsigned int u; } v; v.f = f;
    const unsigned int r = v.u + 0x7FFFu + ((v.u >> 16) & 1u);
    return (unsigned short)(r >> 16);
}

// ---------------- gating: logits, softmax, top-2, aux partials, x->bf16 -----
__global__ __launch_bounds__(256) void moe_gate_kernel(
    const float* __restrict__ x, const float* __restrict__ gw,
    int* __restrict__ e1o, int* __restrict__ e2o,
    float* __restrict__ g1o, float* __restrict__ g2o,
    float* __restrict__ sums, __bf16* __restrict__ xb)
{
    __shared__ float sgw[EE][DD];          // 32 KB
    __shared__ float wp[4][18];
    for (int i = threadIdx.x; i < EE * DD; i += 256) sgw[i >> 10][i & 1023] = gw[i];
    __syncthreads();

    const int wave = threadIdx.x >> 6, lane = threadIdx.x & 63;
    const int gwave = blockIdx.x * 4 + wave;
    const int nwaves = gridDim.x * 4;

    float pa_acc = 0.f, z_acc = 0.f;
    float P_acc[EE] = {0}, p6_acc[EE] = {0};

    for (int t = gwave; t < TT; t += nwaves) {
        float acc[EE] = {0};
        const float* xr = x + (size_t)t * DD;
        __bf16* xbr = xb + (size_t)t * DD;
        #pragma unroll
        for (int i = 0; i < DD / 64; ++i) {
            const float xv = xr[lane + 64 * i];
            xbr[lane + 64 * i] = (__bf16)xv;
            #pragma unroll
            for (int e = 0; e < EE; ++e) acc[e] += xv * sgw[e][lane + 64 * i];
        }
        #pragma unroll
        for (int e = 0; e < EE; ++e) {
            float v = acc[e];
            #pragma unroll
            for (int off = 32; off > 0; off >>= 1) v += __shfl_xor(v, off, 64);
            acc[e] = v;
        }
        if (lane == 0) {
            float mx = acc[0];
            #pragma unroll
            for (int e = 1; e < EE; ++e) mx = fmaxf(mx, acc[e]);
            float pr[EE], p6[EE], se = 0.f, s6 = 0.f;
            #pragma unroll
            for (int e = 0; e < EE; ++e) {
                pr[e] = __expf(acc[e] - mx); se += pr[e];
                p6[e] = __expf((acc[e] - mx) * (1.0f / 1.66f)); s6 += p6[e];
            }
            const float lse = mx + __logf(se);
            z_acc += lse * lse;
            const float ise = 1.f / se, is6 = 1.f / s6;
            #pragma unroll
            for (int e = 0; e < EE; ++e) {
                pr[e] *= ise; p6[e] *= is6;
                P_acc[e] += pr[e]; p6_acc[e] += p6[e];
                pa_acc += p6[e] * (1.f - p6[e]);
            }
            int a = 0;
            #pragma unroll
            for (int e = 1; e < EE; ++e) if (pr[e] > pr[a]) a = e;
            int b = (a == 0) ? 1 : 0;
            #pragma unroll
            for (int e = 0; e < EE; ++e) if (e != a && pr[e] > pr[b]) b = e;
            const float ga = pr[a], gb = pr[b], idn = 1.f / (ga + gb);
            e1o[t] = a; e2o[t] = b;
            g1o[t] = ga * idn; g2o[t] = gb * idn;
        }
    }
    if (lane == 0) {
        wp[wave][0] = pa_acc; wp[wave][1] = z_acc;
        #pragma unroll
        for (int e = 0; e < EE; ++e) { wp[wave][2 + e] = P_acc[e]; wp[wave][10 + e] = p6_acc[e]; }
    }
    __syncthreads();
    if (threadIdx.x < 18) {
        const float s = wp[0][threadIdx.x] + wp[1][threadIdx.x] + wp[2][threadIdx.x] + wp[3][threadIdx.x];
        atomicAdd(&sums[threadIdx.x], s);
    }
}

// ---------------- ordered capacity scan (shuffle-based) ---------------------
__device__ __forceinline__ int fld8(unsigned long long lo, unsigned long long hi, int e) {
    return (int)(((e < 4) ? (lo >> (16 * e)) : (hi >> (16 * (e - 4)))) & 0xFFFFull);
}

__global__ __launch_bounds__(256) void moe_scan_kernel(
    const int* __restrict__ e1i, const int* __restrict__ e2i,
    const float* __restrict__ g1i, const float* __restrict__ g2i,
    const float* __restrict__ rnd,
    int* __restrict__ etok, float* __restrict__ ew,
    int* __restrict__ cnt, float* __restrict__ imp, int* __restrict__ fcnt)
{
    __shared__ unsigned long long wt[4][4];
    __shared__ int lcnt[EE];
    __shared__ float limp[EE];
    const int tid = threadIdx.x, wave = tid >> 6, lane = tid & 63;
    if (tid < EE) { lcnt[tid] = 0; limp[tid] = 0.f; }
    __syncthreads();
    unsigned long long blo1 = 0, bhi1 = 0, blo2 = 0, bhi2 = 0;

    for (int c = 0; c < TT / 256; ++c) {
        const int t = c * 256 + tid;
        const int a1 = e1i[t], a2 = e2i[t];
        const float gg1 = g1i[t], gg2 = g2i[t];
        unsigned long long s_lo1 = (a1 < 4)  ? 1ull << (16 * a1)       : 0ull;
        unsigned long long s_hi1 = (a1 >= 4) ? 1ull << (16 * (a1 - 4)) : 0ull;
        unsigned long long s_lo2 = (a2 < 4)  ? 1ull << (16 * a2)       : 0ull;
        unsigned long long s_hi2 = (a2 >= 4) ? 1ull << (16 * (a2 - 4)) : 0ull;
        #pragma unroll
        for (int off = 1; off < 64; off <<= 1) {
            unsigned long long v;
            v = __shfl_up(s_lo1, off, 64); if (lane >= off) s_lo1 += v;
            v = __shfl_up(s_hi1, off, 64); if (lane >= off) s_hi1 += v;
            v = __shfl_up(s_lo2, off, 64); if (lane >= off) s_lo2 += v;
            v = __shfl_up(s_hi2, off, 64); if (lane >= off) s_hi2 += v;
        }
        if (lane == 63) { wt[wave][0] = s_lo1; wt[wave][1] = s_hi1; wt[wave][2] = s_lo2; wt[wave][3] = s_hi2; }
        __syncthreads();
        unsigned long long o_lo1 = blo1, o_hi1 = bhi1, o_lo2 = blo2, o_hi2 = bhi2;
        #pragma unroll
        for (int ww = 0; ww < 4; ++ww) {
            if (ww < wave) { o_lo1 += wt[ww][0]; o_hi1 += wt[ww][1]; o_lo2 += wt[ww][2]; o_hi2 += wt[ww][3]; }
            blo1 += wt[ww][0]; bhi1 += wt[ww][1]; blo2 += wt[ww][2]; bhi2 += wt[ww][3];
        }
        const int pos1 = fld8(o_lo1 + s_lo1, o_hi1 + s_hi1, a1) - 1;
        const int pos2 = fld8(o_lo2 + s_lo2, o_hi2 + s_hi2, a2) - 1;
        const bool m1 = (pos1 < CAPV);
        const bool m2 = (pos2 < CAPV) && (rnd[t] < 2.f * gg2);
        if (m1) {
            const int idx = atomicAdd(&lcnt[a1], 1);
            etok[a1 * LIST_STRIDE + idx] = t; ew[a1 * LIST_STRIDE + idx] = gg1;
            atomicAdd(&limp[a1], gg1);
        }
        if (m2) {
            const int idx = atomicAdd(&lcnt[a2], 1);
            etok[a2 * LIST_STRIDE + idx] = t; ew[a2 * LIST_STRIDE + idx] = gg2;
            atomicAdd(&limp[a2], gg2);
        }
        __syncthreads();
    }
    if (tid < EE) { cnt[tid] = lcnt[tid]; imp[tid] = limp[tid]; fcnt[tid] = fld8(blo1, bhi1, tid); }
}

// ---------------- aux scalar ------------------------------------------------
__global__ void moe_aux_kernel(const float* __restrict__ sums, const float* __restrict__ imp,
                               const int* __restrict__ fcnt, float* __restrict__ out_aux)
{
    if (threadIdx.x != 0 || blockIdx.x != 0) return;
    const float invT = 1.f / (float)TT;
    const float pa = sums[0] / ((float)TT * (float)EE);
    float pb = 0.f, load = 0.f, msum = 0.f;
    for (int e = 0; e < EE; ++e) {
        const float pm = sums[10 + e] * invT;
        pb += pm * (1.f - pm);
        load += ((float)fcnt[e] * invT) * (sums[2 + e] * invT);
        msum += imp[e];
    }
    pb = 1.f / (float)EE - pb / (float)EE;
    const float penalty = 0.01f * (pa + pb);
    const float z_loss = 0.001f * sums[1] * invT;
    const float load_loss = 0.01f * (float)EE * load;
    const float mean = msum / (float)EE;
    float var = 0.f;
    for (int e = 0; e < EE; ++e) { const float d = imp[e] - mean; var += d * d; }
    var /= (float)EE;
    const float imp_loss = 0.01f * var / (mean * mean);
    *out_aux = penalty + z_loss + load_loss + imp_loss;
}

// ---------------- fp32 [K x N] -> bf16 [N x K] transpose --------------------
// K-tile 64, N-tile 32. grid (K/64, N/32), 256 threads.
__global__ __launch_bounds__(256) void transpose_bf16_kernel(
    const float* __restrict__ in, __bf16* __restrict__ out, int K, int N)
{
    __shared__ float tile[32][65];   // [n][k]
    const int bk = blockIdx.x * 64, bn = blockIdx.y * 32;
    const int tid = threadIdx.x;
    #pragma unroll
    for (int p = 0; p < 8; ++p) {
        const int idx = p * 256 + tid;       // 0..2047
        const int kl = idx >> 5, nl = idx & 31;
        tile[nl][kl] = in[(size_t)(bk + kl) * N + bn + nl];
    }
    __syncthreads();
    #pragma unroll
    for (int p = 0; p < 4; ++p) {
        const int wdx = p * 256 + tid;       // 0..1023
        const int nl = wdx >> 5, c = wdx & 31;
        const unsigned int pk = (unsigned int)f2bf(tile[nl][c * 2])
                              | ((unsigned int)f2bf(tile[nl][c * 2 + 1]) << 16);
        *(unsigned int*)&out[(size_t)(bn + nl) * K + bk + c * 2] = pk;
    }
}

// ---------------- FFN pass 1 (MFMA): H = gelu(Xg @ W1 + b1) -----------------
// C-tile 128x128, BK=32, 4 waves in 2x2, each wave 64x64 (4x4 MFMA frags).
__global__ __launch_bounds__(256) void moe_ffn1_mfma(
    const __bf16* __restrict__ xb, const __bf16* __restrict__ w1T,
    const float* __restrict__ b1, const int* __restrict__ etok,
    const int* __restrict__ cnt, __bf16* __restrict__ H, int e)
{
    const int ce = cnt[e];
    const int m0 = blockIdx.x * 128;
    if (m0 >= ce) return;
    const int n0 = blockIdx.y * 128;
    const int tid = threadIdx.x, lane = tid & 63, w = tid >> 6;
    const int wm = w >> 1, wn = w & 1;

    __shared__ __bf16 As[128 * 32];
    __shared__ __bf16 Bs[128 * 32];
    __shared__ int stok[128];
    if (tid < 128) {
        const int gr = m0 + tid;
        stok[tid] = (gr < ce) ? etok[e * LIST_STRIDE + gr] : 0;
    }
    __syncthreads();

    const int r0 = tid >> 2;                 // staging row within 64-row group
    const int c8 = (tid & 3) * 8;            // bf16-element offset within 32-col row
    const size_t tokA0 = (size_t)stok[r0];
    const size_t tokA1 = (size_t)stok[64 + r0];
    const __bf16* ga0 = xb + tokA0 * DD + c8;
    const __bf16* ga1 = xb + tokA1 * DD + c8;
    const __bf16* gb0 = w1T + (size_t)(n0 + r0) * DD + c8;
    const __bf16* gb1 = w1T + (size_t)(n0 + 64 + r0) * DD + c8;
    __bf16* lA0 = &As[w * 512];
    __bf16* lA1 = &As[2048 + w * 512];
    __bf16* lB0 = &Bs[w * 512];
    __bf16* lB1 = &Bs[2048 + w * 512];

    floatx4 acc[4][4];
    #pragma unroll
    for (int i = 0; i < 4; ++i)
        #pragma unroll
        for (int j = 0; j < 4; ++j) acc[i][j] = floatx4{0.f, 0.f, 0.f, 0.f};

    const int quad = lane >> 4, l16 = lane & 15;
    for (int k0 = 0; k0 < DD; k0 += 32) {
        __syncthreads();
        gl_lds16(ga0 + k0, lA0);
        gl_lds16(ga1 + k0, lA1);
        gl_lds16(gb0 + k0, lB0);
        gl_lds16(gb1 + k0, lB1);
        __syncthreads();
        bf16x8 a[4], b[4];
        #pragma unroll
        for (int i = 0; i < 4; ++i)
            a[i] = *(const bf16x8*)&As[(wm * 64 + i * 16 + l16) * 32 + quad * 8];
        #pragma unroll
        for (int j = 0; j < 4; ++j)
            b[j] = *(const bf16x8*)&Bs[(wn * 64 + j * 16 + l16) * 32 + quad * 8];
        #pragma unroll
        for (int i = 0; i < 4; ++i)
            #pragma unroll
            for (int j = 0; j < 4; ++j)
                acc[i][j] = __builtin_amdgcn_mfma_f32_16x16x32_bf16(a[i], b[j], acc[i][j], 0, 0, 0);
    }

    const float* b1e = b1 + (size_t)e * FF;
    #pragma unroll
    for (int i = 0; i < 4; ++i) {
        const int mrow = m0 + wm * 64 + i * 16 + quad * 4;
        #pragma unroll
        for (int j = 0; j < 4; ++j) {
            const int col = n0 + wn * 64 + j * 16 + l16;
            const float bb = b1e[col];
            #pragma unroll
            for (int r = 0; r < 4; ++r) {
                const float v = acc[i][j][r] + bb;
                const float u = 0.7978845608028654f * (v + 0.044715f * v * v * v);
                const float th = 1.f - 2.f / (__expf(2.f * u) + 1.f);
                H[(size_t)(mrow + r) * FF + col] = (__bf16)(0.5f * v * (1.f + th));
            }
        }
    }
}

// ---------------- FFN pass 2 (MFMA): y += w * (H @ W2 + b2) -----------------
// C-tile 64x128, BK=32, 4 waves in 2x2, each wave 32x64 (2x4 MFMA frags).
__global__ __launch_bounds__(256) void moe_ffn2_mfma(
    const __bf16* __restrict__ H, const __bf16* __restrict__ w2T,
    const float* __restrict__ b2, const int* __restrict__ etok,
    const float* __restrict__ ew, const int* __restrict__ cnt,
    float* __restrict__ y, int e)
{
    const int ce = cnt[e];
    const int m0 = blockIdx.x * 64;
    if (m0 >= ce) return;
    const int n0 = blockIdx.y * 128;
    const int tid = threadIdx.x, lane = tid & 63, w = tid >> 6;
    const int wm = w >> 1, wn = w & 1;

    __shared__ __bf16 As[64 * 32];     // 4 KB
    __shared__ __bf16 Bs[128 * 32];    // 8 KB

    const int r0 = tid >> 2;
    const int c8 = (tid & 3) * 8;
    const __bf16* ga0 = H + (size_t)(m0 + r0) * FF + c8;
    const __bf16* gb0 = w2T + (size_t)(n0 + r0) * FF + c8;
    const __bf16* gb1 = w2T + (size_t)(n0 + 64 + r0) * FF + c8;
    __bf16* lA0 = &As[w * 512];
    __bf16* lB0 = &Bs[w * 512];
    __bf16* lB1 = &Bs[2048 + w * 512];

    floatx4 acc[2][4];
    #pragma unroll
    for (int i = 0; i < 2; ++i)
        #pragma unroll
        for (int j = 0; j < 4; ++j) acc[i][j] = floatx4{0.f, 0.f, 0.f, 0.f};

    const int quad = lane >> 4, l16 = lane & 15;
    for (int k0 = 0; k0 < FF; k0 += 32) {
        __syncthreads();
        gl_lds16(ga0 + k0, lA0);
        gl_lds16(gb0 + k0, lB0);
        gl_lds16(gb1 + k0, lB1);
        __syncthreads();
        bf16x8 a[2], b[4];
        #pragma unroll
        for (int i = 0; i < 2; ++i)
            a[i] = *(const bf16x8*)&As[(wm * 32 + i * 16 + l16) * 32 + quad * 8];
        #pragma unroll
        for (int j = 0; j < 4; ++j)
            b[j] = *(const bf16x8*)&Bs[(wn * 64 + j * 16 + l16) * 32 + quad * 8];
        #pragma unroll
        for (int i = 0; i < 2; ++i)
            #pragma unroll
            for (int j = 0; j < 4; ++j)
                acc[i][j] = __builtin_amdgcn_mfma_f32_16x16x32_bf16(a[i], b[j], acc[i][j], 0, 0, 0);
    }

    const float* b2e = b2 + (size_t)e * DD;
    #pragma unroll
    for (int i = 0; i < 2; ++i) {
        #pragma unroll
        for (int r = 0; r < 4; ++r) {
            const int gr = m0 + wm * 32 + i * 16 + quad * 4 + r;
            if (gr < ce) {
                const size_t tok = (size_t)etok[e * LIST_STRIDE + gr];
                const float wgt = ew[e * LIST_STRIDE + gr];
                #pragma unroll
                for (int j = 0; j < 4; ++j) {
                    const int col = n0 + wn * 64 + j * 16 + l16;
                    float* yp = &y[tok * DD + col];
                    *yp += wgt * (acc[i][j][r] + b2e[col]);
                }
            }
        }
    }
}

// ---------------- launch ----------------------------------------------------
extern "C" void kernel_launch(void* const* d_in, const int* in_sizes, int n_in,
                              void* d_out, int out_size, void* d_ws, size_t ws_size,
                              hipStream_t stream) {
    const float* x   = (const float*)d_in[0];
    const float* gw  = (const float*)d_in[1];
    const float* w1  = (const float*)d_in[2];
    const float* b1  = (const float*)d_in[3];
    const float* w2  = (const float*)d_in[4];
    const float* b2  = (const float*)d_in[5];
    const float* rnd = (const float*)d_in[6];
    float* out = (float*)d_out;

    char* p = (char*)d_ws;
    float* sums = (float*)p;                 // 18 floats
    float* imp  = (float*)(p + 128);         // 8 floats
    int*   fcnt = (int*)(p + 192);           // 8 ints
    int*   cnt  = (int*)(p + 256);           // 8 ints
    p += 512;
    int*   e1v = (int*)p;   p += TT * 4;
    int*   e2v = (int*)p;   p += TT * 4;
    float* g1v = (float*)p; p += TT * 4;
    float* g2v = (float*)p; p += TT * 4;
    int*   etok = (int*)p;  p += EE * LIST_STRIDE * 4;
    float* ewv  = (float*)p; p += EE * LIST_STRIDE * 4;
    uintptr_t q = (((uintptr_t)p) + 255) & ~(uintptr_t)255;
    __bf16* xb  = (__bf16*)q;  q += (size_t)TT * DD * 2;     // 16 MB
    __bf16* w1T = (__bf16*)q;  q += (size_t)FF * DD * 2;     // 8 MB
    __bf16* w2T = (__bf16*)q;  q += (size_t)DD * FF * 2;     // 8 MB
    __bf16* H   = (__bf16*)q;                                // 4096 x FF bf16 = 32 MB

    hipMemsetAsync(sums, 0, 128, stream);
    hipMemsetAsync(d_out, 0, (size_t)TT * DD * sizeof(float), stream);

    moe_gate_kernel<<<128, 256, 0, stream>>>(x, gw, e1v, e2v, g1v, g2v, sums, xb);
    moe_scan_kernel<<<1, 256, 0, stream>>>(e1v, e2v, g1v, g2v, rnd, etok, ewv, cnt, imp, fcnt);
    moe_aux_kernel<<<1, 64, 0, stream>>>(sums, imp, fcnt, out + (size_t)TT * DD);

    for (int e = 0; e < EE; ++e) {
        // w1[e]: [D x FF] fp32 -> w1T: [FF x D] bf16 ; w2[e]: [FF x D] -> w2T: [D x FF]
        transpose_bf16_kernel<<<dim3(DD / 64, FF / 32), 256, 0, stream>>>(w1 + (size_t)e * DD * FF, w1T, DD, FF);
        transpose_bf16_kernel<<<dim3(FF / 64, DD / 32), 256, 0, stream>>>(w2 + (size_t)e * FF * DD, w2T, FF, DD);
        moe_ffn1_mfma<<<dim3(32, FF / 128), 256, 0, stream>>>(xb, w1T, b1, etok, cnt, H, e);
        moe_ffn2_mfma<<<dim3(64, DD / 128), 256, 0, stream>>>(H, w2T, b2, etok, ewv, cnt, out, e);
    }
}

// Round 3
// 1218.444 us; speedup vs baseline: 3.7395x; 1.1954x over previous
//
#include <hip/hip_runtime.h>
#include <math.h>
#include <stdint.h>

#define DD 1024
#define EE 8
#define FF 4096
#define CAPV 2048
#define TT 8192
#define LIST_STRIDE 4096   // per-expert entry capacity (2*CAP)

typedef __bf16 bf16x8 __attribute__((ext_vector_type(8)));
typedef float floatx4 __attribute__((ext_vector_type(4)));

typedef __attribute__((address_space(3))) unsigned int as3_uint;
typedef __attribute__((address_space(1))) const unsigned int as1_uint;

__device__ __forceinline__ void gl_lds16(const void* g, void* l) {
    __builtin_amdgcn_global_load_lds((as1_uint*)g, (as3_uint*)l, 16, 0, 0);
}

__device__ __forceinline__ unsigned short f2bf(float f) {
    union { float f; unsigned int u; } v; v.f = f;
    const unsigned int r = v.u + 0x7FFFu + ((v.u >> 16) & 1u);
    return (unsigned short)(r >> 16);
}

// ---------------- gating: logits, softmax, top-2, aux partials, x->bf16 -----
// sums layout: [0]=pa [1]=z [2..9]=P [10..17]=p6 [18..25]=n1 counts (as float)
__global__ __launch_bounds__(256) void moe_gate_kernel(
    const float* __restrict__ x, const float* __restrict__ gw,
    int* __restrict__ e1o, int* __restrict__ e2o,
    float* __restrict__ g1o, float* __restrict__ g2o,
    float* __restrict__ sums, __bf16* __restrict__ xb)
{
    __shared__ float sgw[EE][DD];          // 32 KB
    __shared__ float wp[4][26];
    for (int i = threadIdx.x; i < EE * DD; i += 256) sgw[i >> 10][i & 1023] = gw[i];
    __syncthreads();

    const int wave = threadIdx.x >> 6, lane = threadIdx.x & 63;
    const int gwave = blockIdx.x * 4 + wave;
    const int nwaves = gridDim.x * 4;

    float pa_acc = 0.f, z_acc = 0.f;
    float P_acc[EE] = {0}, p6_acc[EE] = {0};
    int n1_acc[EE] = {0};

    for (int t = gwave; t < TT; t += nwaves) {
        float acc[EE] = {0};
        const float* xr = x + (size_t)t * DD;
        __bf16* xbr = xb + (size_t)t * DD;
        #pragma unroll
        for (int i = 0; i < DD / 64; ++i) {
            const float xv = xr[lane + 64 * i];
            xbr[lane + 64 * i] = (__bf16)xv;
            #pragma unroll
            for (int e = 0; e < EE; ++e) acc[e] += xv * sgw[e][lane + 64 * i];
        }
        #pragma unroll
        for (int e = 0; e < EE; ++e) {
            float v = acc[e];
            #pragma unroll
            for (int off = 32; off > 0; off >>= 1) v += __shfl_xor(v, off, 64);
            acc[e] = v;
        }
        if (lane == 0) {
            float mx = acc[0];
            #pragma unroll
            for (int e = 1; e < EE; ++e) mx = fmaxf(mx, acc[e]);
            float pr[EE], p6[EE], se = 0.f, s6 = 0.f;
            #pragma unroll
            for (int e = 0; e < EE; ++e) {
                pr[e] = __expf(acc[e] - mx); se += pr[e];
                p6[e] = __expf((acc[e] - mx) * (1.0f / 1.66f)); s6 += p6[e];
            }
            const float lse = mx + __logf(se);
            z_acc += lse * lse;
            const float ise = 1.f / se, is6 = 1.f / s6;
            #pragma unroll
            for (int e = 0; e < EE; ++e) {
                pr[e] *= ise; p6[e] *= is6;
                P_acc[e] += pr[e]; p6_acc[e] += p6[e];
                pa_acc += p6[e] * (1.f - p6[e]);
            }
            int a = 0;
            #pragma unroll
            for (int e = 1; e < EE; ++e) if (pr[e] > pr[a]) a = e;
            int b = (a == 0) ? 1 : 0;
            #pragma unroll
            for (int e = 0; e < EE; ++e) if (e != a && pr[e] > pr[b]) b = e;
            n1_acc[a]++;
            const float ga = pr[a], gb = pr[b], idn = 1.f / (ga + gb);
            e1o[t] = a; e2o[t] = b;
            g1o[t] = ga * idn; g2o[t] = gb * idn;
        }
    }
    if (lane == 0) {
        wp[wave][0] = pa_acc; wp[wave][1] = z_acc;
        #pragma unroll
        for (int e = 0; e < EE; ++e) {
            wp[wave][2 + e] = P_acc[e]; wp[wave][10 + e] = p6_acc[e];
            wp[wave][18 + e] = (float)n1_acc[e];
        }
    }
    __syncthreads();
    if (threadIdx.x < 26) {
        const float s = wp[0][threadIdx.x] + wp[1][threadIdx.x] + wp[2][threadIdx.x] + wp[3][threadIdx.x];
        atomicAdd(&sums[threadIdx.x], s);
    }
}

// ---------------- parallel ordered capacity scan: 16 blocks (slot, expert) --
__global__ __launch_bounds__(256) void moe_scan_kernel(
    const int* __restrict__ e1i, const int* __restrict__ e2i,
    const float* __restrict__ g1i, const float* __restrict__ g2i,
    const float* __restrict__ rnd, const float* __restrict__ sums,
    int* __restrict__ etok, float* __restrict__ ew,
    int* __restrict__ cnt1, int* __restrict__ cnt2,
    float* __restrict__ imp1, float* __restrict__ imp2)
{
    const int bid = blockIdx.x, slot = bid >> 3, e = bid & 7;
    const int tid = threadIdx.x, wave = tid >> 6, lane = tid & 63;
    __shared__ int wtA[4], wtB[4];
    __shared__ float red[256];
    const int* ev = slot ? e2i : e1i;
    const float* gv = slot ? g2i : g1i;
    const int base = slot ? min((int)sums[18 + e], CAPV) : 0;

    int runTot = 0, runM = 0;
    float limp = 0.f;
    for (int c = 0; c < TT / 256; ++c) {
        const int t = c * 256 + tid;
        const int sel = (ev[t] == e) ? 1 : 0;
        const float w = gv[t];
        int ps = sel;
        #pragma unroll
        for (int off = 1; off < 64; off <<= 1) { int v = __shfl_up(ps, off, 64); if (lane >= off) ps += v; }
        if (lane == 63) wtA[wave] = ps;
        __syncthreads();
        int wpre = 0, ctot = 0;
        #pragma unroll
        for (int ww = 0; ww < 4; ++ww) { if (ww < wave) wpre += wtA[ww]; ctot += wtA[ww]; }
        const int pos = runTot + wpre + ps - 1;      // valid when sel
        int m, idx;
        if (slot == 0) {
            m = sel && (pos < CAPV);
            idx = pos;
        } else {
            m = (sel && (pos < CAPV) && (rnd[t] < 2.f * w)) ? 1 : 0;
            int pm = m;
            #pragma unroll
            for (int off = 1; off < 64; off <<= 1) { int v = __shfl_up(pm, off, 64); if (lane >= off) pm += v; }
            if (lane == 63) wtB[wave] = pm;
            __syncthreads();
            int wpm = 0, mtot = 0;
            #pragma unroll
            for (int ww = 0; ww < 4; ++ww) { if (ww < wave) wpm += wtB[ww]; mtot += wtB[ww]; }
            idx = runM + wpm + pm - 1;
            runM += mtot;
        }
        if (m) {
            etok[e * LIST_STRIDE + base + idx] = t;
            ew[e * LIST_STRIDE + base + idx] = w;
            limp += w;
        }
        runTot += ctot;
        __syncthreads();
    }
    red[tid] = limp; __syncthreads();
    for (int s = 128; s > 0; s >>= 1) { if (tid < s) red[tid] += red[tid + s]; __syncthreads(); }
    if (tid == 0) {
        if (slot == 0) { cnt1[e] = min(runTot, CAPV); imp1[e] = red[0]; }
        else           { cnt2[e] = runM;              imp2[e] = red[0]; }
    }
}

// ---------------- aux scalar ------------------------------------------------
__global__ void moe_aux_kernel(const float* __restrict__ sums,
                               const float* __restrict__ imp1, const float* __restrict__ imp2,
                               float* __restrict__ out_aux)
{
    if (threadIdx.x != 0 || blockIdx.x != 0) return;
    const float invT = 1.f / (float)TT;
    const float pa = sums[0] / ((float)TT * (float)EE);
    float pb = 0.f, load = 0.f, msum = 0.f;
    float im[EE];
    for (int e = 0; e < EE; ++e) {
        const float pm = sums[10 + e] * invT;
        pb += pm * (1.f - pm);
        load += (sums[18 + e] * invT) * (sums[2 + e] * invT);
        im[e] = imp1[e] + imp2[e];
        msum += im[e];
    }
    pb = 1.f / (float)EE - pb / (float)EE;
    const float penalty = 0.01f * (pa + pb);
    const float z_loss = 0.001f * sums[1] * invT;
    const float load_loss = 0.01f * (float)EE * load;
    const float mean = msum / (float)EE;
    float var = 0.f;
    for (int e = 0; e < EE; ++e) { const float d = im[e] - mean; var += d * d; }
    var /= (float)EE;
    const float imp_loss = 0.01f * var / (mean * mean);
    *out_aux = penalty + z_loss + load_loss + imp_loss;
}

// ---------------- fp32 [e][K x N] -> bf16 [e][N x K] transpose --------------
__global__ __launch_bounds__(256) void transpose_bf16_kernel(
    const float* __restrict__ in, __bf16* __restrict__ out, int K, int N)
{
    __shared__ float tile[32][65];   // [n][k]
    const int e = blockIdx.z;
    const float* ine = in + (size_t)e * K * N;
    __bf16* oute = out + (size_t)e * K * N;
    const int bk = blockIdx.x * 64, bn = blockIdx.y * 32;
    const int tid = threadIdx.x;
    #pragma unroll
    for (int p = 0; p < 8; ++p) {
        const int idx = p * 256 + tid;       // 0..2047
        const int kl = idx >> 5, nl = idx & 31;
        tile[nl][kl] = ine[(size_t)(bk + kl) * N + bn + nl];
    }
    __syncthreads();
    #pragma unroll
    for (int p = 0; p < 4; ++p) {
        const int wdx = p * 256 + tid;       // 0..1023
        const int nl = wdx >> 5, c = wdx & 31;
        const unsigned int pk = (unsigned int)f2bf(tile[nl][c * 2])
                              | ((unsigned int)f2bf(tile[nl][c * 2 + 1]) << 16);
        *(unsigned int*)&oute[(size_t)(bn + nl) * K + bk + c * 2] = pk;
    }
}

// ---------------- FFN pass 1 (MFMA, all experts): H = gelu(Xg @ W1 + b1) ----
// C-tile 128x128, BK=32, 4 waves 2x2, each wave 64x64 (4x4 MFMA frags).
__global__ __launch_bounds__(256) void moe_ffn1_mfma(
    const __bf16* __restrict__ xb, const __bf16* __restrict__ w1T,
    const float* __restrict__ b1, const int* __restrict__ etok,
    const int* __restrict__ cnt1, const int* __restrict__ cnt2,
    __bf16* __restrict__ H)
{
    const int e = blockIdx.z;
    const int ce = cnt1[e] + cnt2[e];
    const int m0 = blockIdx.x * 128;
    if (m0 >= ce) return;
    const int n0 = blockIdx.y * 128;
    const int tid = threadIdx.x, lane = tid & 63, w = tid >> 6;
    const int wm = w >> 1, wn = w & 1;

    __shared__ __bf16 As[128 * 32];
    __shared__ __bf16 Bs[128 * 32];
    __shared__ int stok[128];
    if (tid < 128) {
        const int gr = m0 + tid;
        stok[tid] = (gr < ce) ? etok[e * LIST_STRIDE + gr] : 0;
    }
    __syncthreads();

    const int r0 = tid >> 2;                 // staging row 0..63
    const int c8 = (tid & 3) * 8;
    const size_t tokA0 = (size_t)stok[r0];
    const size_t tokA1 = (size_t)stok[64 + r0];
    const __bf16* ga0 = xb + tokA0 * DD + c8;
    const __bf16* ga1 = xb + tokA1 * DD + c8;
    const __bf16* gb0 = w1T + (size_t)e * FF * DD + (size_t)(n0 + r0) * DD + c8;
    const __bf16* gb1 = w1T + (size_t)e * FF * DD + (size_t)(n0 + 64 + r0) * DD + c8;
    __bf16* lA0 = &As[w * 512];
    __bf16* lA1 = &As[2048 + w * 512];
    __bf16* lB0 = &Bs[w * 512];
    __bf16* lB1 = &Bs[2048 + w * 512];

    floatx4 acc[4][4];
    #pragma unroll
    for (int i = 0; i < 4; ++i)
        #pragma unroll
        for (int j = 0; j < 4; ++j) acc[i][j] = floatx4{0.f, 0.f, 0.f, 0.f};

    const int quad = lane >> 4, l16 = lane & 15;
    for (int k0 = 0; k0 < DD; k0 += 32) {
        __syncthreads();
        gl_lds16(ga0 + k0, lA0);
        gl_lds16(ga1 + k0, lA1);
        gl_lds16(gb0 + k0, lB0);
        gl_lds16(gb1 + k0, lB1);
        __syncthreads();
        bf16x8 a[4], b[4];
        #pragma unroll
        for (int i = 0; i < 4; ++i)
            a[i] = *(const bf16x8*)&As[(wm * 64 + i * 16 + l16) * 32 + quad * 8];
        #pragma unroll
        for (int j = 0; j < 4; ++j)
            b[j] = *(const bf16x8*)&Bs[(wn * 64 + j * 16 + l16) * 32 + quad * 8];
        #pragma unroll
        for (int i = 0; i < 4; ++i)
            #pragma unroll
            for (int j = 0; j < 4; ++j)
                acc[i][j] = __builtin_amdgcn_mfma_f32_16x16x32_bf16(a[i], b[j], acc[i][j], 0, 0, 0);
    }

    const float* b1e = b1 + (size_t)e * FF;
    #pragma unroll
    for (int i = 0; i < 4; ++i) {
        const int mrow = m0 + wm * 64 + i * 16 + quad * 4;
        #pragma unroll
        for (int j = 0; j < 4; ++j) {
            const int col = n0 + wn * 64 + j * 16 + l16;
            const float bb = b1e[col];
            #pragma unroll
            for (int r = 0; r < 4; ++r) {
                const float v = acc[i][j][r] + bb;
                const float u = 0.7978845608028654f * (v + 0.044715f * v * v * v);
                const float th = 1.f - 2.f / (__expf(2.f * u) + 1.f);
                H[((size_t)e * LIST_STRIDE + mrow + r) * FF + col] = (__bf16)(0.5f * v * (1.f + th));
            }
        }
    }
}

// ---------------- FFN pass 2 (MFMA, all experts, one slot per launch) -------
// y[tok] += w * (H @ W2 + b2). C-tile 128x128, K=FF. Plain += is race-free:
// within a slot each token appears at most once; slots are separate launches.
__global__ __launch_bounds__(256) void moe_ffn2_mfma(
    const __bf16* __restrict__ H, const __bf16* __restrict__ w2T,
    const float* __restrict__ b2, const int* __restrict__ etok,
    const float* __restrict__ ew, const int* __restrict__ cnt1,
    const int* __restrict__ cnt2, float* __restrict__ y, int slot)
{
    const int e = blockIdx.z;
    const int base = slot ? cnt1[e] : 0;
    const int mycnt = slot ? cnt2[e] : cnt1[e];
    if (blockIdx.x * 128 >= mycnt) return;
    const int m0 = base + blockIdx.x * 128;
    const int limit = base + mycnt;
    const int n0 = blockIdx.y * 128;
    const int tid = threadIdx.x, lane = tid & 63, w = tid >> 6;
    const int wm = w >> 1, wn = w & 1;

    __shared__ __bf16 As[128 * 32];
    __shared__ __bf16 Bs[128 * 32];

    const int r0 = tid >> 2;
    const int c8 = (tid & 3) * 8;
    const __bf16* ga0 = H + ((size_t)e * LIST_STRIDE + m0 + r0) * FF + c8;
    const __bf16* ga1 = H + ((size_t)e * LIST_STRIDE + m0 + 64 + r0) * FF + c8;
    const __bf16* gb0 = w2T + (size_t)e * DD * FF + (size_t)(n0 + r0) * FF + c8;
    const __bf16* gb1 = w2T + (size_t)e * DD * FF + (size_t)(n0 + 64 + r0) * FF + c8;
    __bf16* lA0 = &As[w * 512];
    __bf16* lA1 = &As[2048 + w * 512];
    __bf16* lB0 = &Bs[w * 512];
    __bf16* lB1 = &Bs[2048 + w * 512];

    floatx4 acc[4][4];
    #pragma unroll
    for (int i = 0; i < 4; ++i)
        #pragma unroll
        for (int j = 0; j < 4; ++j) acc[i][j] = floatx4{0.f, 0.f, 0.f, 0.f};

    const int quad = lane >> 4, l16 = lane & 15;
    for (int k0 = 0; k0 < FF; k0 += 32) {
        __syncthreads();
        gl_lds16(ga0 + k0, lA0);
        gl_lds16(ga1 + k0, lA1);
        gl_lds16(gb0 + k0, lB0);
        gl_lds16(gb1 + k0, lB1);
        __syncthreads();
        bf16x8 a[4], b[4];
        #pragma unroll
        for (int i = 0; i < 4; ++i)
            a[i] = *(const bf16x8*)&As[(wm * 64 + i * 16 + l16) * 32 + quad * 8];
        #pragma unroll
        for (int j = 0; j < 4; ++j)
            b[j] = *(const bf16x8*)&Bs[(wn * 64 + j * 16 + l16) * 32 + quad * 8];
        #pragma unroll
        for (int i = 0; i < 4; ++i)
            #pragma unroll
            for (int j = 0; j < 4; ++j)
                acc[i][j] = __builtin_amdgcn_mfma_f32_16x16x32_bf16(a[i], b[j], acc[i][j], 0, 0, 0);
    }

    const float* b2e = b2 + (size_t)e * DD;
    #pragma unroll
    for (int i = 0; i < 4; ++i) {
        #pragma unroll
        for (int r = 0; r < 4; ++r) {
            const int gr = m0 + wm * 64 + i * 16 + quad * 4 + r;
            if (gr < limit) {
                const size_t tok = (size_t)etok[e * LIST_STRIDE + gr];
                const float wgt = ew[e * LIST_STRIDE + gr];
                #pragma unroll
                for (int j = 0; j < 4; ++j) {
                    const int col = n0 + wn * 64 + j * 16 + l16;
                    float* yp = &y[tok * DD + col];
                    *yp += wgt * (acc[i][j][r] + b2e[col]);
                }
            }
        }
    }
}

// ---------------- launch ----------------------------------------------------
extern "C" void kernel_launch(void* const* d_in, const int* in_sizes, int n_in,
                              void* d_out, int out_size, void* d_ws, size_t ws_size,
                              hipStream_t stream) {
    const float* x   = (const float*)d_in[0];
    const float* gw  = (const float*)d_in[1];
    const float* w1  = (const float*)d_in[2];
    const float* b1  = (const float*)d_in[3];
    const float* w2  = (const float*)d_in[4];
    const float* b2  = (const float*)d_in[5];
    const float* rnd = (const float*)d_in[6];
    float* out = (float*)d_out;

    char* p = (char*)d_ws;
    float* sums = (float*)p;                 // 26 floats
    float* imp1 = (float*)(p + 128);         // 8 floats
    float* imp2 = (float*)(p + 160);         // 8 floats
    int*   cnt1 = (int*)(p + 192);           // 8 ints
    int*   cnt2 = (int*)(p + 224);           // 8 ints
    p += 512;
    int*   e1v = (int*)p;   p += TT * 4;
    int*   e2v = (int*)p;   p += TT * 4;
    float* g1v = (float*)p; p += TT * 4;
    float* g2v = (float*)p; p += TT * 4;
    int*   etok = (int*)p;  p += EE * LIST_STRIDE * 4;
    float* ewv  = (float*)p; p += EE * LIST_STRIDE * 4;
    uintptr_t q = (((uintptr_t)p) + 255) & ~(uintptr_t)255;
    __bf16* xb  = (__bf16*)q;  q += (size_t)TT * DD * 2;             // 16 MB
    __bf16* w1T = (__bf16*)q;  q += (size_t)EE * FF * DD * 2;        // 64 MB
    __bf16* w2T = (__bf16*)q;  q += (size_t)EE * DD * FF * 2;        // 64 MB
    __bf16* H   = (__bf16*)q;                                        // 8*4096*FF bf16 = 256 MB

    hipMemsetAsync(sums, 0, 128, stream);
    hipMemsetAsync(d_out, 0, (size_t)TT * DD * sizeof(float), stream);

    moe_gate_kernel<<<256, 256, 0, stream>>>(x, gw, e1v, e2v, g1v, g2v, sums, xb);
    moe_scan_kernel<<<16, 256, 0, stream>>>(e1v, e2v, g1v, g2v, rnd, sums,
                                            etok, ewv, cnt1, cnt2, imp1, imp2);
    moe_aux_kernel<<<1, 64, 0, stream>>>(sums, imp1, imp2, out + (size_t)TT * DD);

    // all-expert weight transposes: w1 [e][D][FF] -> w1T [e][FF][D]; w2 -> w2T
    transpose_bf16_kernel<<<dim3(DD / 64, FF / 32, EE), 256, 0, stream>>>(w1, w1T, DD, FF);
    transpose_bf16_kernel<<<dim3(FF / 64, DD / 32, EE), 256, 0, stream>>>(w2, w2T, FF, DD);

    moe_ffn1_mfma<<<dim3(32, FF / 128, EE), 256, 0, stream>>>(xb, w1T, b1, etok, cnt1, cnt2, H);
    moe_ffn2_mfma<<<dim3(16, DD / 128, EE), 256, 0, stream>>>(H, w2T, b2, etok, ewv, cnt1, cnt2, out, 0);
    moe_ffn2_mfma<<<dim3(16, DD / 128, EE), 256, 0, stream>>>(H, w2T, b2, etok, ewv, cnt1, cnt2, out, 1);
}

// Round 4
// 887.902 us; speedup vs baseline: 5.1316x; 1.3723x over previous
//
#include <hip/hip_runtime.h>
#include <math.h>
#include <stdint.h>

#define DD 1024
#define EE 8
#define FF 4096
#define CAPV 2048
#define TT 8192
#define LIST_STRIDE 4096   // per-expert entry capacity (2*CAP)

typedef __bf16 bf16x8 __attribute__((ext_vector_type(8)));
typedef __bf16 bf16x4 __attribute__((ext_vector_type(4)));
typedef float floatx4 __attribute__((ext_vector_type(4)));

typedef __attribute__((address_space(3))) unsigned int as3_uint;
typedef __attribute__((address_space(1))) const unsigned int as1_uint;

__device__ __forceinline__ void gl_lds16(const void* g, void* l) {
    __builtin_amdgcn_global_load_lds((as1_uint*)g, (as3_uint*)l, 16, 0, 0);
}

__device__ __forceinline__ unsigned short f2bf(float f) {
    union { float f; unsigned int u; } v; v.f = f;
    const unsigned int r = v.u + 0x7FFFu + ((v.u >> 16) & 1u);
    return (unsigned short)(r >> 16);
}

// ---------------- gating: logits, softmax, top-2, aux partials, x->bf16 -----
// sums layout: [0]=pa [1]=z [2..9]=P [10..17]=p6 [18..25]=n1 counts (as float)
__global__ __launch_bounds__(256) void moe_gate_kernel(
    const float* __restrict__ x, const float* __restrict__ gw,
    int* __restrict__ e1o, int* __restrict__ e2o,
    float* __restrict__ g1o, float* __restrict__ g2o,
    float* __restrict__ sums, __bf16* __restrict__ xb)
{
    __shared__ float sgw[EE][DD];          // 32 KB
    __shared__ float wp[4][26];
    for (int i = threadIdx.x; i < EE * DD; i += 256) sgw[i >> 10][i & 1023] = gw[i];
    __syncthreads();

    const int wave = threadIdx.x >> 6, lane = threadIdx.x & 63;
    const int gwave = blockIdx.x * 4 + wave;
    const int nwaves = gridDim.x * 4;

    float pa_acc = 0.f, z_acc = 0.f;
    float P_acc[EE] = {0}, p6_acc[EE] = {0};
    int n1_acc[EE] = {0};

    for (int t = gwave; t < TT; t += nwaves) {
        float acc[EE] = {0};
        const float* xr = x + (size_t)t * DD;
        __bf16* xbr = xb + (size_t)t * DD;
        #pragma unroll
        for (int i = 0; i < DD / 64; ++i) {
            const float xv = xr[lane + 64 * i];
            xbr[lane + 64 * i] = (__bf16)xv;
            #pragma unroll
            for (int e = 0; e < EE; ++e) acc[e] += xv * sgw[e][lane + 64 * i];
        }
        #pragma unroll
        for (int e = 0; e < EE; ++e) {
            float v = acc[e];
            #pragma unroll
            for (int off = 32; off > 0; off >>= 1) v += __shfl_xor(v, off, 64);
            acc[e] = v;
        }
        if (lane == 0) {
            float mx = acc[0];
            #pragma unroll
            for (int e = 1; e < EE; ++e) mx = fmaxf(mx, acc[e]);
            float pr[EE], p6[EE], se = 0.f, s6 = 0.f;
            #pragma unroll
            for (int e = 0; e < EE; ++e) {
                pr[e] = __expf(acc[e] - mx); se += pr[e];
                p6[e] = __expf((acc[e] - mx) * (1.0f / 1.66f)); s6 += p6[e];
            }
            const float lse = mx + __logf(se);
            z_acc += lse * lse;
            const float ise = 1.f / se, is6 = 1.f / s6;
            #pragma unroll
            for (int e = 0; e < EE; ++e) {
                pr[e] *= ise; p6[e] *= is6;
                P_acc[e] += pr[e]; p6_acc[e] += p6[e];
                pa_acc += p6[e] * (1.f - p6[e]);
            }
            int a = 0;
            #pragma unroll
            for (int e = 1; e < EE; ++e) if (pr[e] > pr[a]) a = e;
            int b = (a == 0) ? 1 : 0;
            #pragma unroll
            for (int e = 0; e < EE; ++e) if (e != a && pr[e] > pr[b]) b = e;
            n1_acc[a]++;
            const float ga = pr[a], gb = pr[b], idn = 1.f / (ga + gb);
            e1o[t] = a; e2o[t] = b;
            g1o[t] = ga * idn; g2o[t] = gb * idn;
        }
    }
    if (lane == 0) {
        wp[wave][0] = pa_acc; wp[wave][1] = z_acc;
        #pragma unroll
        for (int e = 0; e < EE; ++e) {
            wp[wave][2 + e] = P_acc[e]; wp[wave][10 + e] = p6_acc[e];
            wp[wave][18 + e] = (float)n1_acc[e];
        }
    }
    __syncthreads();
    if (threadIdx.x < 26) {
        const float s = wp[0][threadIdx.x] + wp[1][threadIdx.x] + wp[2][threadIdx.x] + wp[3][threadIdx.x];
        atomicAdd(&sums[threadIdx.x], s);
    }
}

// ---------------- parallel ordered capacity scan: 16 blocks (slot, expert) --
__global__ __launch_bounds__(256) void moe_scan_kernel(
    const int* __restrict__ e1i, const int* __restrict__ e2i,
    const float* __restrict__ g1i, const float* __restrict__ g2i,
    const float* __restrict__ rnd, const float* __restrict__ sums,
    int* __restrict__ etok, float* __restrict__ ew,
    int* __restrict__ cnt1, int* __restrict__ cnt2,
    float* __restrict__ imp1, float* __restrict__ imp2)
{
    const int bid = blockIdx.x, slot = bid >> 3, e = bid & 7;
    const int tid = threadIdx.x, wave = tid >> 6, lane = tid & 63;
    __shared__ int wtA[4], wtB[4];
    __shared__ float red[256];
    const int* ev = slot ? e2i : e1i;
    const float* gv = slot ? g2i : g1i;
    const int base = slot ? min((int)sums[18 + e], CAPV) : 0;

    int runTot = 0, runM = 0;
    float limp = 0.f;
    for (int c = 0; c < TT / 256; ++c) {
        const int t = c * 256 + tid;
        const int sel = (ev[t] == e) ? 1 : 0;
        const float w = gv[t];
        int ps = sel;
        #pragma unroll
        for (int off = 1; off < 64; off <<= 1) { int v = __shfl_up(ps, off, 64); if (lane >= off) ps += v; }
        if (lane == 63) wtA[wave] = ps;
        __syncthreads();
        int wpre = 0, ctot = 0;
        #pragma unroll
        for (int ww = 0; ww < 4; ++ww) { if (ww < wave) wpre += wtA[ww]; ctot += wtA[ww]; }
        const int pos = runTot + wpre + ps - 1;      // valid when sel
        int m, idx;
        if (slot == 0) {
            m = sel && (pos < CAPV);
            idx = pos;
        } else {
            m = (sel && (pos < CAPV) && (rnd[t] < 2.f * w)) ? 1 : 0;
            int pm = m;
            #pragma unroll
            for (int off = 1; off < 64; off <<= 1) { int v = __shfl_up(pm, off, 64); if (lane >= off) pm += v; }
            if (lane == 63) wtB[wave] = pm;
            __syncthreads();
            int wpm = 0, mtot = 0;
            #pragma unroll
            for (int ww = 0; ww < 4; ++ww) { if (ww < wave) wpm += wtB[ww]; mtot += wtB[ww]; }
            idx = runM + wpm + pm - 1;
            runM += mtot;
        }
        if (m) {
            etok[e * LIST_STRIDE + base + idx] = t;
            ew[e * LIST_STRIDE + base + idx] = w;
            limp += w;
        }
        runTot += ctot;
        __syncthreads();
    }
    red[tid] = limp; __syncthreads();
    for (int s = 128; s > 0; s >>= 1) { if (tid < s) red[tid] += red[tid + s]; __syncthreads(); }
    if (tid == 0) {
        if (slot == 0) { cnt1[e] = min(runTot, CAPV); imp1[e] = red[0]; }
        else           { cnt2[e] = runM;              imp2[e] = red[0]; }
    }
}

// ---------------- aux scalar ------------------------------------------------
__global__ void moe_aux_kernel(const float* __restrict__ sums,
                               const float* __restrict__ imp1, const float* __restrict__ imp2,
                               float* __restrict__ out_aux)
{
    if (threadIdx.x != 0 || blockIdx.x != 0) return;
    const float invT = 1.f / (float)TT;
    const float pa = sums[0] / ((float)TT * (float)EE);
    float pb = 0.f, load = 0.f, msum = 0.f;
    float im[EE];
    for (int e = 0; e < EE; ++e) {
        const float pm = sums[10 + e] * invT;
        pb += pm * (1.f - pm);
        load += (sums[18 + e] * invT) * (sums[2 + e] * invT);
        im[e] = imp1[e] + imp2[e];
        msum += im[e];
    }
    pb = 1.f / (float)EE - pb / (float)EE;
    const float penalty = 0.01f * (pa + pb);
    const float z_loss = 0.001f * sums[1] * invT;
    const float load_loss = 0.01f * (float)EE * load;
    const float mean = msum / (float)EE;
    float var = 0.f;
    for (int e = 0; e < EE; ++e) { const float d = im[e] - mean; var += d * d; }
    var /= (float)EE;
    const float imp_loss = 0.01f * var / (mean * mean);
    *out_aux = penalty + z_loss + load_loss + imp_loss;
}

// ---------------- fp32 [e][K x N] -> bf16 [e][N x K] transpose --------------
__global__ __launch_bounds__(256) void transpose_bf16_kernel(
    const float* __restrict__ in, __bf16* __restrict__ out, int K, int N)
{
    __shared__ float tile[32][65];   // [n][k]
    const int e = blockIdx.z;
    const float* ine = in + (size_t)e * K * N;
    __bf16* oute = out + (size_t)e * K * N;
    const int bk = blockIdx.x * 64, bn = blockIdx.y * 32;
    const int tid = threadIdx.x;
    #pragma unroll
    for (int p = 0; p < 8; ++p) {
        const int idx = p * 256 + tid;       // 0..2047
        const int kl = idx >> 5, nl = idx & 31;
        tile[nl][kl] = ine[(size_t)(bk + kl) * N + bn + nl];
    }
    __syncthreads();
    #pragma unroll
    for (int p = 0; p < 4; ++p) {
        const int wdx = p * 256 + tid;       // 0..1023
        const int nl = wdx >> 5, c = wdx & 31;
        const unsigned int pk = (unsigned int)f2bf(tile[nl][c * 2])
                              | ((unsigned int)f2bf(tile[nl][c * 2 + 1]) << 16);
        *(unsigned int*)&oute[(size_t)(bn + nl) * K + bk + c * 2] = pk;
    }
}

// ---------------- FFN pass 1 (MFMA, pipelined, all experts) -----------------
// H = gelu(Xg @ W1 + b1). C-tile 128x128, BK=32, dbuf LDS, 1 barrier/iter.
// 1D grid 8192: xcd=f&7, s=f>>3, group g=xcd*32+(s>>5) -> e=g>>5, n0t=g&31,
// m-tile = s&31 (members of a group contiguous per XCD -> B-tile L2 reuse).
__global__ __launch_bounds__(256, 4) void moe_ffn1_mfma(
    const __bf16* __restrict__ xb, const __bf16* __restrict__ w1T,
    const float* __restrict__ b1, const int* __restrict__ etok,
    const int* __restrict__ cnt1, const int* __restrict__ cnt2,
    __bf16* __restrict__ H)
{
    const int f = blockIdx.x;
    const int xcd = f & 7, s = f >> 3;
    const int g = xcd * 32 + (s >> 5);
    const int e = g >> 5, n0 = (g & 31) * 128;
    const int m0 = (s & 31) * 128;
    const int ce = cnt1[e] + cnt2[e];
    if (m0 >= ce) return;
    const int tid = threadIdx.x, lane = tid & 63, w = tid >> 6;
    const int wm = w >> 1, wn = w & 1;

    __shared__ __bf16 As[2][4096];
    __shared__ __bf16 Bs[2][4096];
    __shared__ int stok[128];
    if (tid < 128) {
        const int gr = m0 + tid;
        stok[tid] = (gr < ce) ? etok[e * LIST_STRIDE + gr] : 0;
    }
    __syncthreads();

    // staging: thread -> (row r=tid>>2, chunk c=tid&3); source chunk XOR-swizzled
    const int csrc8 = (((tid & 3) ^ ((tid >> 3) & 3)) * 8);
    const int r0 = tid >> 2;
    const __bf16* aptr0 = xb + (size_t)stok[r0] * DD + csrc8;
    const __bf16* aptr1 = xb + (size_t)stok[64 + r0] * DD + csrc8;
    const __bf16* bbase = w1T + (size_t)e * FF * DD;
    const __bf16* bptr0 = bbase + (size_t)(n0 + r0) * DD + csrc8;
    const __bf16* bptr1 = bbase + (size_t)(n0 + 64 + r0) * DD + csrc8;
    const int wofs = w * 512;

    floatx4 acc[4][4];
    #pragma unroll
    for (int i = 0; i < 4; ++i)
        #pragma unroll
        for (int j = 0; j < 4; ++j) acc[i][j] = floatx4{0.f, 0.f, 0.f, 0.f};

    const int quad = lane >> 4, l16 = lane & 15;
    const int swq = (quad ^ ((l16 >> 1) & 3)) * 8;

    // preload k=0 into buf 0
    gl_lds16(aptr0, &As[0][wofs]);
    gl_lds16(aptr1, &As[0][2048 + wofs]);
    gl_lds16(bptr0, &Bs[0][wofs]);
    gl_lds16(bptr1, &Bs[0][2048 + wofs]);

    int cur = 0;
    for (int k0 = 0; k0 < DD; k0 += 32) {
        __syncthreads();                      // drains vmcnt -> buf[cur] ready
        if (k0 + 32 < DD) {
            const int nb = cur ^ 1, kn = k0 + 32;
            gl_lds16(aptr0 + kn, &As[nb][wofs]);
            gl_lds16(aptr1 + kn, &As[nb][2048 + wofs]);
            gl_lds16(bptr0 + kn, &Bs[nb][wofs]);
            gl_lds16(bptr1 + kn, &Bs[nb][2048 + wofs]);
        }
        bf16x8 a[4], b[4];
        #pragma unroll
        for (int i = 0; i < 4; ++i)
            a[i] = *(const bf16x8*)&As[cur][(wm * 64 + i * 16 + l16) * 32 + swq];
        #pragma unroll
        for (int j = 0; j < 4; ++j)
            b[j] = *(const bf16x8*)&Bs[cur][(wn * 64 + j * 16 + l16) * 32 + swq];
        #pragma unroll
        for (int i = 0; i < 4; ++i)
            #pragma unroll
            for (int j = 0; j < 4; ++j)
                acc[i][j] = __builtin_amdgcn_mfma_f32_16x16x32_bf16(b[j], a[i], acc[i][j], 0, 0, 0);
        cur ^= 1;
    }

    // epilogue: acc[i][j] regs = 4 consecutive n-cols at one m-row -> 8B stores
    const float* b1e = b1 + (size_t)e * FF;
    #pragma unroll
    for (int i = 0; i < 4; ++i) {
        const int mrow = m0 + wm * 64 + i * 16 + l16;
        __bf16* hrow = H + ((size_t)e * LIST_STRIDE + mrow) * FF;
        #pragma unroll
        for (int j = 0; j < 4; ++j) {
            const int col0 = n0 + wn * 64 + j * 16 + quad * 4;
            const float4 bb = *(const float4*)&b1e[col0];
            float vv[4] = {acc[i][j][0] + bb.x, acc[i][j][1] + bb.y,
                           acc[i][j][2] + bb.z, acc[i][j][3] + bb.w};
            bf16x4 pk;
            #pragma unroll
            for (int r = 0; r < 4; ++r) {
                const float v = vv[r];
                const float u = 0.7978845608028654f * (v + 0.044715f * v * v * v);
                const float th = 1.f - 2.f / (__expf(2.f * u) + 1.f);
                pk[r] = (__bf16)(0.5f * v * (1.f + th));
            }
            *(bf16x4*)&hrow[col0] = pk;
        }
    }
}

// ---------------- FFN pass 2 (MFMA, pipelined, one slot per launch) ---------
// y[tok] (=|+=) w * (H @ W2 + b2). C-tile 128x128, K=FF, dbuf, 1 barrier/iter.
// slot0 stores (d_out pre-zeroed), slot1 read-modify-writes: race-free.
// 1D grid 1024: xcd=f&7, s=f>>3, g=xcd*8+(s>>4) -> e=g>>3, n0t=g&7, m=s&15.
__global__ __launch_bounds__(256, 4) void moe_ffn2_mfma(
    const __bf16* __restrict__ H, const __bf16* __restrict__ w2T,
    const float* __restrict__ b2, const int* __restrict__ etok,
    const float* __restrict__ ew, const int* __restrict__ cnt1,
    const int* __restrict__ cnt2, float* __restrict__ y, const int slot)
{
    const int f = blockIdx.x;
    const int xcd = f & 7, s = f >> 3;
    const int g = xcd * 8 + (s >> 4);
    const int e = g >> 3, n0 = (g & 7) * 128;
    const int base = slot ? cnt1[e] : 0;
    const int mycnt = slot ? cnt2[e] : cnt1[e];
    const int mt = s & 15;
    if (mt * 128 >= mycnt) return;
    const int m0 = base + mt * 128;
    const int limit = base + mycnt;
    const int tid = threadIdx.x, lane = tid & 63, w = tid >> 6;
    const int wm = w >> 1, wn = w & 1;

    __shared__ __bf16 As[2][4096];
    __shared__ __bf16 Bs[2][4096];
    __shared__ int stok[128];
    __shared__ float swt[128];
    if (tid < 128) {
        const int gr = m0 + tid;
        const bool ok = (gr < limit);
        stok[tid] = ok ? etok[e * LIST_STRIDE + gr] : -1;
        swt[tid] = ok ? ew[e * LIST_STRIDE + gr] : 0.f;
    }
    __syncthreads();

    const int csrc8 = (((tid & 3) ^ ((tid >> 3) & 3)) * 8);
    const int r0 = tid >> 2;
    const __bf16* aptr0 = H + ((size_t)e * LIST_STRIDE + m0 + r0) * FF + csrc8;
    const __bf16* aptr1 = H + ((size_t)e * LIST_STRIDE + m0 + 64 + r0) * FF + csrc8;
    const __bf16* bbase = w2T + (size_t)e * DD * FF;
    const __bf16* bptr0 = bbase + (size_t)(n0 + r0) * FF + csrc8;
    const __bf16* bptr1 = bbase + (size_t)(n0 + 64 + r0) * FF + csrc8;
    const int wofs = w * 512;

    floatx4 acc[4][4];
    #pragma unroll
    for (int i = 0; i < 4; ++i)
        #pragma unroll
        for (int j = 0; j < 4; ++j) acc[i][j] = floatx4{0.f, 0.f, 0.f, 0.f};

    const int quad = lane >> 4, l16 = lane & 15;
    const int swq = (quad ^ ((l16 >> 1) & 3)) * 8;

    gl_lds16(aptr0, &As[0][wofs]);
    gl_lds16(aptr1, &As[0][2048 + wofs]);
    gl_lds16(bptr0, &Bs[0][wofs]);
    gl_lds16(bptr1, &Bs[0][2048 + wofs]);

    int cur = 0;
    for (int k0 = 0; k0 < FF; k0 += 32) {
        __syncthreads();
        if (k0 + 32 < FF) {
            const int nb = cur ^ 1, kn = k0 + 32;
            gl_lds16(aptr0 + kn, &As[nb][wofs]);
            gl_lds16(aptr1 + kn, &As[nb][2048 + wofs]);
            gl_lds16(bptr0 + kn, &Bs[nb][wofs]);
            gl_lds16(bptr1 + kn, &Bs[nb][2048 + wofs]);
        }
        bf16x8 a[4], b[4];
        #pragma unroll
        for (int i = 0; i < 4; ++i)
            a[i] = *(const bf16x8*)&As[cur][(wm * 64 + i * 16 + l16) * 32 + swq];
        #pragma unroll
        for (int j = 0; j < 4; ++j)
            b[j] = *(const bf16x8*)&Bs[cur][(wn * 64 + j * 16 + l16) * 32 + swq];
        #pragma unroll
        for (int i = 0; i < 4; ++i)
            #pragma unroll
            for (int j = 0; j < 4; ++j)
                acc[i][j] = __builtin_amdgcn_mfma_f32_16x16x32_bf16(b[j], a[i], acc[i][j], 0, 0, 0);
        cur ^= 1;
    }

    const float* b2e = b2 + (size_t)e * DD;
    #pragma unroll
    for (int i = 0; i < 4; ++i) {
        const int lrow = wm * 64 + i * 16 + l16;
        const int tok = stok[lrow];
        if (tok >= 0) {
            const float wgt = swt[lrow];
            float* yrow = y + (size_t)tok * DD;
            #pragma unroll
            for (int j = 0; j < 4; ++j) {
                const int col0 = n0 + wn * 64 + j * 16 + quad * 4;
                const float4 bb = *(const float4*)&b2e[col0];
                float4 v;
                v.x = wgt * (acc[i][j][0] + bb.x);
                v.y = wgt * (acc[i][j][1] + bb.y);
                v.z = wgt * (acc[i][j][2] + bb.z);
                v.w = wgt * (acc[i][j][3] + bb.w);
                float4* yp = (float4*)&yrow[col0];
                if (slot == 0) {
                    *yp = v;
                } else {
                    float4 o = *yp;
                    o.x += v.x; o.y += v.y; o.z += v.z; o.w += v.w;
                    *yp = o;
                }
            }
        }
    }
}

// ---------------- launch ----------------------------------------------------
extern "C" void kernel_launch(void* const* d_in, const int* in_sizes, int n_in,
                              void* d_out, int out_size, void* d_ws, size_t ws_size,
                              hipStream_t stream) {
    const float* x   = (const float*)d_in[0];
    const float* gw  = (const float*)d_in[1];
    const float* w1  = (const float*)d_in[2];
    const float* b1  = (const float*)d_in[3];
    const float* w2  = (const float*)d_in[4];
    const float* b2  = (const float*)d_in[5];
    const float* rnd = (const float*)d_in[6];
    float* out = (float*)d_out;

    char* p = (char*)d_ws;
    float* sums = (float*)p;                 // 26 floats
    float* imp1 = (float*)(p + 128);         // 8 floats
    float* imp2 = (float*)(p + 160);         // 8 floats
    int*   cnt1 = (int*)(p + 192);           // 8 ints
    int*   cnt2 = (int*)(p + 224);           // 8 ints
    p += 512;
    int*   e1v = (int*)p;   p += TT * 4;
    int*   e2v = (int*)p;   p += TT * 4;
    float* g1v = (float*)p; p += TT * 4;
    float* g2v = (float*)p; p += TT * 4;
    int*   etok = (int*)p;  p += EE * LIST_STRIDE * 4;
    float* ewv  = (float*)p; p += EE * LIST_STRIDE * 4;
    uintptr_t q = (((uintptr_t)p) + 255) & ~(uintptr_t)255;
    __bf16* xb  = (__bf16*)q;  q += (size_t)TT * DD * 2;             // 16 MB
    __bf16* w1T = (__bf16*)q;  q += (size_t)EE * FF * DD * 2;        // 64 MB
    __bf16* w2T = (__bf16*)q;  q += (size_t)EE * DD * FF * 2;        // 64 MB
    __bf16* H   = (__bf16*)q;                                        // 256 MB

    hipMemsetAsync(sums, 0, 128, stream);
    hipMemsetAsync(d_out, 0, (size_t)TT * DD * sizeof(float), stream);

    moe_gate_kernel<<<256, 256, 0, stream>>>(x, gw, e1v, e2v, g1v, g2v, sums, xb);
    moe_scan_kernel<<<16, 256, 0, stream>>>(e1v, e2v, g1v, g2v, rnd, sums,
                                            etok, ewv, cnt1, cnt2, imp1, imp2);
    moe_aux_kernel<<<1, 64, 0, stream>>>(sums, imp1, imp2, out + (size_t)TT * DD);

    transpose_bf16_kernel<<<dim3(DD / 64, FF / 32, EE), 256, 0, stream>>>(w1, w1T, DD, FF);
    transpose_bf16_kernel<<<dim3(FF / 64, DD / 32, EE), 256, 0, stream>>>(w2, w2T, FF, DD);

    moe_ffn1_mfma<<<8192, 256, 0, stream>>>(xb, w1T, b1, etok, cnt1, cnt2, H);
    moe_ffn2_mfma<<<1024, 256, 0, stream>>>(H, w2T, b2, etok, ewv, cnt1, cnt2, out, 0);
    moe_ffn2_mfma<<<1024, 256, 0, stream>>>(H, w2T, b2, etok, ewv, cnt1, cnt2, out, 1);
}

// Round 5
// 751.179 us; speedup vs baseline: 6.0656x; 1.1820x over previous
//
#include <hip/hip_runtime.h>
#include <math.h>
#include <stdint.h>

#define DD 1024
#define EE 8
#define FF 4096
#define CAPV 2048
#define TT 8192
#define LIST_STRIDE 4096   // per-expert entry capacity (2*CAP)

typedef __bf16 bf16x8 __attribute__((ext_vector_type(8)));
typedef __bf16 bf16x4 __attribute__((ext_vector_type(4)));
typedef float floatx4 __attribute__((ext_vector_type(4)));

typedef __attribute__((address_space(3))) unsigned int as3_uint;
typedef __attribute__((address_space(1))) const unsigned int as1_uint;

__device__ __forceinline__ void gl_lds16(const void* g, void* l) {
    __builtin_amdgcn_global_load_lds((as1_uint*)g, (as3_uint*)l, 16, 0, 0);
}

__device__ __forceinline__ unsigned short f2bf(float f) {
    union { float f; unsigned int u; } v; v.f = f;
    const unsigned int r = v.u + 0x7FFFu + ((v.u >> 16) & 1u);
    return (unsigned short)(r >> 16);
}

// ---------------- gating: logits, softmax, top-2, aux partials, x->bf16 -----
// sums layout: [0]=pa [1]=z [2..9]=P [10..17]=p6 [18..25]=n1 counts (as float)
__global__ __launch_bounds__(256) void moe_gate_kernel(
    const float* __restrict__ x, const float* __restrict__ gw,
    int* __restrict__ e1o, int* __restrict__ e2o,
    float* __restrict__ g1o, float* __restrict__ g2o,
    float* __restrict__ sums, __bf16* __restrict__ xb)
{
    __shared__ float sgw[EE][DD];          // 32 KB
    __shared__ float wp[4][26];
    for (int i = threadIdx.x; i < EE * DD; i += 256) sgw[i >> 10][i & 1023] = gw[i];
    __syncthreads();

    const int wave = threadIdx.x >> 6, lane = threadIdx.x & 63;
    const int gwave = blockIdx.x * 4 + wave;
    const int nwaves = gridDim.x * 4;

    float pa_acc = 0.f, z_acc = 0.f;
    float P_acc[EE] = {0}, p6_acc[EE] = {0};
    int n1_acc[EE] = {0};

    for (int t = gwave; t < TT; t += nwaves) {
        float acc[EE] = {0};
        const float* xr = x + (size_t)t * DD;
        __bf16* xbr = xb + (size_t)t * DD;
        #pragma unroll
        for (int i = 0; i < DD / 64; ++i) {
            const float xv = xr[lane + 64 * i];
            xbr[lane + 64 * i] = (__bf16)xv;
            #pragma unroll
            for (int e = 0; e < EE; ++e) acc[e] += xv * sgw[e][lane + 64 * i];
        }
        #pragma unroll
        for (int e = 0; e < EE; ++e) {
            float v = acc[e];
            #pragma unroll
            for (int off = 32; off > 0; off >>= 1) v += __shfl_xor(v, off, 64);
            acc[e] = v;
        }
        if (lane == 0) {
            float mx = acc[0];
            #pragma unroll
            for (int e = 1; e < EE; ++e) mx = fmaxf(mx, acc[e]);
            float pr[EE], p6[EE], se = 0.f, s6 = 0.f;
            #pragma unroll
            for (int e = 0; e < EE; ++e) {
                pr[e] = __expf(acc[e] - mx); se += pr[e];
                p6[e] = __expf((acc[e] - mx) * (1.0f / 1.66f)); s6 += p6[e];
            }
            const float lse = mx + __logf(se);
            z_acc += lse * lse;
            const float ise = 1.f / se, is6 = 1.f / s6;
            #pragma unroll
            for (int e = 0; e < EE; ++e) {
                pr[e] *= ise; p6[e] *= is6;
                P_acc[e] += pr[e]; p6_acc[e] += p6[e];
                pa_acc += p6[e] * (1.f - p6[e]);
            }
            int a = 0;
            #pragma unroll
            for (int e = 1; e < EE; ++e) if (pr[e] > pr[a]) a = e;
            int b = (a == 0) ? 1 : 0;
            #pragma unroll
            for (int e = 0; e < EE; ++e) if (e != a && pr[e] > pr[b]) b = e;
            n1_acc[a]++;
            const float ga = pr[a], gb = pr[b], idn = 1.f / (ga + gb);
            e1o[t] = a; e2o[t] = b;
            g1o[t] = ga * idn; g2o[t] = gb * idn;
        }
    }
    if (lane == 0) {
        wp[wave][0] = pa_acc; wp[wave][1] = z_acc;
        #pragma unroll
        for (int e = 0; e < EE; ++e) {
            wp[wave][2 + e] = P_acc[e]; wp[wave][10 + e] = p6_acc[e];
            wp[wave][18 + e] = (float)n1_acc[e];
        }
    }
    __syncthreads();
    if (threadIdx.x < 26) {
        const float s = wp[0][threadIdx.x] + wp[1][threadIdx.x] + wp[2][threadIdx.x] + wp[3][threadIdx.x];
        atomicAdd(&sums[threadIdx.x], s);
    }
}

// ---------------- parallel ordered capacity scan: 16 blocks (slot, expert) --
// Writes per-expert entry token lists (etok) and per-token entry rows p1/p2
// (global O/H row index, -1 if dropped).
__global__ __launch_bounds__(256) void moe_scan_kernel(
    const int* __restrict__ e1i, const int* __restrict__ e2i,
    const float* __restrict__ g1i, const float* __restrict__ g2i,
    const float* __restrict__ rnd, const float* __restrict__ sums,
    int* __restrict__ etok, int* __restrict__ p1o, int* __restrict__ p2o,
    int* __restrict__ cnt1, int* __restrict__ cnt2,
    float* __restrict__ imp1, float* __restrict__ imp2)
{
    const int bid = blockIdx.x, slot = bid >> 3, e = bid & 7;
    const int tid = threadIdx.x, wave = tid >> 6, lane = tid & 63;
    __shared__ int wtA[4], wtB[4];
    __shared__ float red[256];
    const int* ev = slot ? e2i : e1i;
    const float* gv = slot ? g2i : g1i;
    int* po = slot ? p2o : p1o;
    const int base = slot ? min((int)sums[18 + e], CAPV) : 0;

    int runTot = 0, runM = 0;
    float limp = 0.f;
    for (int c = 0; c < TT / 256; ++c) {
        const int t = c * 256 + tid;
        const int sel = (ev[t] == e) ? 1 : 0;
        const float w = gv[t];
        int ps = sel;
        #pragma unroll
        for (int off = 1; off < 64; off <<= 1) { int v = __shfl_up(ps, off, 64); if (lane >= off) ps += v; }
        if (lane == 63) wtA[wave] = ps;
        __syncthreads();
        int wpre = 0, ctot = 0;
        #pragma unroll
        for (int ww = 0; ww < 4; ++ww) { if (ww < wave) wpre += wtA[ww]; ctot += wtA[ww]; }
        const int pos = runTot + wpre + ps - 1;      // valid when sel
        int m, idx;
        if (slot == 0) {
            m = sel && (pos < CAPV);
            idx = pos;
        } else {
            m = (sel && (pos < CAPV) && (rnd[t] < 2.f * w)) ? 1 : 0;
            int pm = m;
            #pragma unroll
            for (int off = 1; off < 64; off <<= 1) { int v = __shfl_up(pm, off, 64); if (lane >= off) pm += v; }
            if (lane == 63) wtB[wave] = pm;
            __syncthreads();
            int wpm = 0, mtot = 0;
            #pragma unroll
            for (int ww = 0; ww < 4; ++ww) { if (ww < wave) wpm += wtB[ww]; mtot += wtB[ww]; }
            idx = runM + wpm + pm - 1;
            runM += mtot;
        }
        if (sel) po[t] = m ? (e * LIST_STRIDE + base + idx) : -1;
        if (m) {
            etok[e * LIST_STRIDE + base + idx] = t;
            limp += w;
        }
        runTot += ctot;
        __syncthreads();
    }
    red[tid] = limp; __syncthreads();
    for (int s = 128; s > 0; s >>= 1) { if (tid < s) red[tid] += red[tid + s]; __syncthreads(); }
    if (tid == 0) {
        if (slot == 0) { cnt1[e] = min(runTot, CAPV); imp1[e] = red[0]; }
        else           { cnt2[e] = runM;              imp2[e] = red[0]; }
    }
}

// ---------------- aux scalar ------------------------------------------------
__global__ void moe_aux_kernel(const float* __restrict__ sums,
                               const float* __restrict__ imp1, const float* __restrict__ imp2,
                               float* __restrict__ out_aux)
{
    if (threadIdx.x != 0 || blockIdx.x != 0) return;
    const float invT = 1.f / (float)TT;
    const float pa = sums[0] / ((float)TT * (float)EE);
    float pb = 0.f, load = 0.f, msum = 0.f;
    float im[EE];
    for (int e = 0; e < EE; ++e) {
        const float pm = sums[10 + e] * invT;
        pb += pm * (1.f - pm);
        load += (sums[18 + e] * invT) * (sums[2 + e] * invT);
        im[e] = imp1[e] + imp2[e];
        msum += im[e];
    }
    pb = 1.f / (float)EE - pb / (float)EE;
    const float penalty = 0.01f * (pa + pb);
    const float z_loss = 0.001f * sums[1] * invT;
    const float load_loss = 0.01f * (float)EE * load;
    const float mean = msum / (float)EE;
    float var = 0.f;
    for (int e = 0; e < EE; ++e) { const float d = im[e] - mean; var += d * d; }
    var /= (float)EE;
    const float imp_loss = 0.01f * var / (mean * mean);
    *out_aux = penalty + z_loss + load_loss + imp_loss;
}

// ---------------- fp32 [e][K x N] -> bf16 [e][N x K] transpose --------------
__global__ __launch_bounds__(256) void transpose_bf16_kernel(
    const float* __restrict__ in, __bf16* __restrict__ out, int K, int N)
{
    __shared__ float tile[32][65];   // [n][k]
    const int e = blockIdx.z;
    const float* ine = in + (size_t)e * K * N;
    __bf16* oute = out + (size_t)e * K * N;
    const int bk = blockIdx.x * 64, bn = blockIdx.y * 32;
    const int tid = threadIdx.x;
    #pragma unroll
    for (int p = 0; p < 8; ++p) {
        const int idx = p * 256 + tid;       // 0..2047
        const int kl = idx >> 5, nl = idx & 31;
        tile[nl][kl] = ine[(size_t)(bk + kl) * N + bn + nl];
    }
    __syncthreads();
    #pragma unroll
    for (int p = 0; p < 4; ++p) {
        const int wdx = p * 256 + tid;       // 0..1023
        const int nl = wdx >> 5, c = wdx & 31;
        const unsigned int pk = (unsigned int)f2bf(tile[nl][c * 2])
                              | ((unsigned int)f2bf(tile[nl][c * 2 + 1]) << 16);
        *(unsigned int*)&oute[(size_t)(bn + nl) * K + bk + c * 2] = pk;
    }
}

// ---------------- FFN pass 1 (MFMA, pipelined, all experts) -----------------
// H = gelu(Xg @ W1 + b1). C-tile 128x128, BK=32, dbuf LDS (32768 B -> 5
// blocks/CU), 1 barrier/iter. 1D grid 8192 XCD-swizzled.
__global__ __launch_bounds__(256, 4) void moe_ffn1_mfma(
    const __bf16* __restrict__ xb, const __bf16* __restrict__ w1T,
    const float* __restrict__ b1, const int* __restrict__ etok,
    const int* __restrict__ cnt1, const int* __restrict__ cnt2,
    __bf16* __restrict__ H)
{
    const int f = blockIdx.x;
    const int xcd = f & 7, s = f >> 3;
    const int g = xcd * 32 + (s >> 5);
    const int e = g >> 5, n0 = (g & 31) * 128;
    const int m0 = (s & 31) * 128;
    const int ce = cnt1[e] + cnt2[e];
    if (m0 >= ce) return;
    const int tid = threadIdx.x, lane = tid & 63, w = tid >> 6;
    const int wm = w >> 1, wn = w & 1;

    __shared__ __bf16 As[2][4096];   // 16 KB
    __shared__ __bf16 Bs[2][4096];   // 16 KB  (total 32768 B exactly)

    // staging: thread -> (row r=tid>>2, chunk c=tid&3); source chunk XOR-swizzled
    const int csrc8 = (((tid & 3) ^ ((tid >> 3) & 3)) * 8);
    const int r0 = tid >> 2;
    const int gr0 = m0 + r0, gr1 = m0 + 64 + r0;
    const int tok0 = (gr0 < ce) ? etok[e * LIST_STRIDE + gr0] : 0;
    const int tok1 = (gr1 < ce) ? etok[e * LIST_STRIDE + gr1] : 0;
    const __bf16* aptr0 = xb + (size_t)tok0 * DD + csrc8;
    const __bf16* aptr1 = xb + (size_t)tok1 * DD + csrc8;
    const __bf16* bbase = w1T + (size_t)e * FF * DD;
    const __bf16* bptr0 = bbase + (size_t)(n0 + r0) * DD + csrc8;
    const __bf16* bptr1 = bbase + (size_t)(n0 + 64 + r0) * DD + csrc8;
    const int wofs = w * 512;

    floatx4 acc[4][4];
    #pragma unroll
    for (int i = 0; i < 4; ++i)
        #pragma unroll
        for (int j = 0; j < 4; ++j) acc[i][j] = floatx4{0.f, 0.f, 0.f, 0.f};

    const int quad = lane >> 4, l16 = lane & 15;
    const int swq = (quad ^ ((l16 >> 1) & 3)) * 8;

    gl_lds16(aptr0, &As[0][wofs]);
    gl_lds16(aptr1, &As[0][2048 + wofs]);
    gl_lds16(bptr0, &Bs[0][wofs]);
    gl_lds16(bptr1, &Bs[0][2048 + wofs]);

    int cur = 0;
    for (int k0 = 0; k0 < DD; k0 += 32) {
        __syncthreads();                      // drains vmcnt -> buf[cur] ready
        if (k0 + 32 < DD) {
            const int nb = cur ^ 1, kn = k0 + 32;
            gl_lds16(aptr0 + kn, &As[nb][wofs]);
            gl_lds16(aptr1 + kn, &As[nb][2048 + wofs]);
            gl_lds16(bptr0 + kn, &Bs[nb][wofs]);
            gl_lds16(bptr1 + kn, &Bs[nb][2048 + wofs]);
        }
        bf16x8 a[4], b[4];
        #pragma unroll
        for (int i = 0; i < 4; ++i)
            a[i] = *(const bf16x8*)&As[cur][(wm * 64 + i * 16 + l16) * 32 + swq];
        #pragma unroll
        for (int j = 0; j < 4; ++j)
            b[j] = *(const bf16x8*)&Bs[cur][(wn * 64 + j * 16 + l16) * 32 + swq];
        #pragma unroll
        for (int i = 0; i < 4; ++i)
            #pragma unroll
            for (int j = 0; j < 4; ++j)
                acc[i][j] = __builtin_amdgcn_mfma_f32_16x16x32_bf16(b[j], a[i], acc[i][j], 0, 0, 0);
        cur ^= 1;
    }

    // epilogue: acc[i][j] regs = 4 consecutive n-cols at one m-row -> 8B stores
    const float* b1e = b1 + (size_t)e * FF;
    #pragma unroll
    for (int i = 0; i < 4; ++i) {
        const int mrow = m0 + wm * 64 + i * 16 + l16;
        __bf16* hrow = H + ((size_t)e * LIST_STRIDE + mrow) * FF;
        #pragma unroll
        for (int j = 0; j < 4; ++j) {
            const int col0 = n0 + wn * 64 + j * 16 + quad * 4;
            const float4 bb = *(const float4*)&b1e[col0];
            float vv[4] = {acc[i][j][0] + bb.x, acc[i][j][1] + bb.y,
                           acc[i][j][2] + bb.z, acc[i][j][3] + bb.w};
            bf16x4 pk;
            #pragma unroll
            for (int r = 0; r < 4; ++r) {
                const float v = vv[r];
                const float u = 0.7978845608028654f * (v + 0.044715f * v * v * v);
                const float th = 1.f - 2.f / (__expf(2.f * u) + 1.f);
                pk[r] = (__bf16)(0.5f * v * (1.f + th));
            }
            *(bf16x4*)&hrow[col0] = pk;
        }
    }
}

// ---------------- FFN pass 2 (MFMA, single launch, dense O output) ----------
// O[row] = H[row] @ W2 + b2 (bf16, no scatter, no weights). C-tile 128x128,
// K=FF, dbuf, 1 barrier/iter. 1D grid 2048 XCD-swizzled.
__global__ __launch_bounds__(256, 4) void moe_ffn2_mfma(
    const __bf16* __restrict__ H, const __bf16* __restrict__ w2T,
    const float* __restrict__ b2, const int* __restrict__ cnt1,
    const int* __restrict__ cnt2, __bf16* __restrict__ O)
{
    const int f = blockIdx.x;
    const int xcd = f & 7, s = f >> 3;               // s in [0,256)
    const int g = xcd * 8 + (s >> 5);                // 64 groups = (e, n-tile)
    const int e = g >> 3, n0 = (g & 7) * 128;
    const int m0 = (s & 31) * 128;
    const int ce = cnt1[e] + cnt2[e];
    if (m0 >= ce) return;
    const int tid = threadIdx.x, lane = tid & 63, w = tid >> 6;
    const int wm = w >> 1, wn = w & 1;

    __shared__ __bf16 As[2][4096];
    __shared__ __bf16 Bs[2][4096];

    const int csrc8 = (((tid & 3) ^ ((tid >> 3) & 3)) * 8);
    const int r0 = tid >> 2;
    const __bf16* aptr0 = H + ((size_t)e * LIST_STRIDE + m0 + r0) * FF + csrc8;
    const __bf16* aptr1 = H + ((size_t)e * LIST_STRIDE + m0 + 64 + r0) * FF + csrc8;
    const __bf16* bbase = w2T + (size_t)e * DD * FF;
    const __bf16* bptr0 = bbase + (size_t)(n0 + r0) * FF + csrc8;
    const __bf16* bptr1 = bbase + (size_t)(n0 + 64 + r0) * FF + csrc8;
    const int wofs = w * 512;

    floatx4 acc[4][4];
    #pragma unroll
    for (int i = 0; i < 4; ++i)
        #pragma unroll
        for (int j = 0; j < 4; ++j) acc[i][j] = floatx4{0.f, 0.f, 0.f, 0.f};

    const int quad = lane >> 4, l16 = lane & 15;
    const int swq = (quad ^ ((l16 >> 1) & 3)) * 8;

    gl_lds16(aptr0, &As[0][wofs]);
    gl_lds16(aptr1, &As[0][2048 + wofs]);
    gl_lds16(bptr0, &Bs[0][wofs]);
    gl_lds16(bptr1, &Bs[0][2048 + wofs]);

    int cur = 0;
    for (int k0 = 0; k0 < FF; k0 += 32) {
        __syncthreads();
        if (k0 + 32 < FF) {
            const int nb = cur ^ 1, kn = k0 + 32;
            gl_lds16(aptr0 + kn, &As[nb][wofs]);
            gl_lds16(aptr1 + kn, &As[nb][2048 + wofs]);
            gl_lds16(bptr0 + kn, &Bs[nb][wofs]);
            gl_lds16(bptr1 + kn, &Bs[nb][2048 + wofs]);
        }
        bf16x8 a[4], b[4];
        #pragma unroll
        for (int i = 0; i < 4; ++i)
            a[i] = *(const bf16x8*)&As[cur][(wm * 64 + i * 16 + l16) * 32 + swq];
        #pragma unroll
        for (int j = 0; j < 4; ++j)
            b[j] = *(const bf16x8*)&Bs[cur][(wn * 64 + j * 16 + l16) * 32 + swq];
        #pragma unroll
        for (int i = 0; i < 4; ++i)
            #pragma unroll
            for (int j = 0; j < 4; ++j)
                acc[i][j] = __builtin_amdgcn_mfma_f32_16x16x32_bf16(b[j], a[i], acc[i][j], 0, 0, 0);
        cur ^= 1;
    }

    const float* b2e = b2 + (size_t)e * DD;
    #pragma unroll
    for (int i = 0; i < 4; ++i) {
        const int lrow = wm * 64 + i * 16 + l16;
        const int grow = m0 + lrow;
        if (grow < ce) {
            __bf16* orow = O + ((size_t)e * LIST_STRIDE + grow) * DD;
            #pragma unroll
            for (int j = 0; j < 4; ++j) {
                const int col0 = n0 + wn * 64 + j * 16 + quad * 4;
                const float4 bb = *(const float4*)&b2e[col0];
                bf16x4 pk;
                pk[0] = (__bf16)(acc[i][j][0] + bb.x);
                pk[1] = (__bf16)(acc[i][j][1] + bb.y);
                pk[2] = (__bf16)(acc[i][j][2] + bb.z);
                pk[3] = (__bf16)(acc[i][j][3] + bb.w);
                *(bf16x4*)&orow[col0] = pk;
            }
        }
    }
}

// ---------------- combine: y[t] = g1*O[p1[t]] + g2*O[p2[t]] -----------------
__global__ __launch_bounds__(256) void moe_combine_kernel(
    const __bf16* __restrict__ O, const float* __restrict__ g1v,
    const float* __restrict__ g2v, const int* __restrict__ p1v,
    const int* __restrict__ p2v, float* __restrict__ y)
{
    const int t = blockIdx.x;
    const int col = threadIdx.x * 4;
    const int p1 = p1v[t], p2 = p2v[t];
    float4 r = make_float4(0.f, 0.f, 0.f, 0.f);
    if (p1 >= 0) {
        const float g = g1v[t];
        const bf16x4 v = *(const bf16x4*)&O[(size_t)p1 * DD + col];
        r.x += g * (float)v[0]; r.y += g * (float)v[1];
        r.z += g * (float)v[2]; r.w += g * (float)v[3];
    }
    if (p2 >= 0) {
        const float g = g2v[t];
        const bf16x4 v = *(const bf16x4*)&O[(size_t)p2 * DD + col];
        r.x += g * (float)v[0]; r.y += g * (float)v[1];
        r.z += g * (float)v[2]; r.w += g * (float)v[3];
    }
    *(float4*)&y[(size_t)t * DD + col] = r;
}

// ---------------- launch ----------------------------------------------------
extern "C" void kernel_launch(void* const* d_in, const int* in_sizes, int n_in,
                              void* d_out, int out_size, void* d_ws, size_t ws_size,
                              hipStream_t stream) {
    const float* x   = (const float*)d_in[0];
    const float* gw  = (const float*)d_in[1];
    const float* w1  = (const float*)d_in[2];
    const float* b1  = (const float*)d_in[3];
    const float* w2  = (const float*)d_in[4];
    const float* b2  = (const float*)d_in[5];
    const float* rnd = (const float*)d_in[6];
    float* out = (float*)d_out;

    char* p = (char*)d_ws;
    float* sums = (float*)p;                 // 26 floats
    float* imp1 = (float*)(p + 128);         // 8 floats
    float* imp2 = (float*)(p + 160);         // 8 floats
    int*   cnt1 = (int*)(p + 192);           // 8 ints
    int*   cnt2 = (int*)(p + 224);           // 8 ints
    p += 512;
    int*   e1v = (int*)p;   p += TT * 4;
    int*   e2v = (int*)p;   p += TT * 4;
    float* g1v = (float*)p; p += TT * 4;
    float* g2v = (float*)p; p += TT * 4;
    int*   p1v = (int*)p;   p += TT * 4;
    int*   p2v = (int*)p;   p += TT * 4;
    int*   etok = (int*)p;  p += EE * LIST_STRIDE * 4;
    uintptr_t q = (((uintptr_t)p) + 255) & ~(uintptr_t)255;
    __bf16* xb  = (__bf16*)q;  q += (size_t)TT * DD * 2;             // 16 MB
    __bf16* w1T = (__bf16*)q;  q += (size_t)EE * FF * DD * 2;        // 64 MB
    __bf16* w2T = (__bf16*)q;  q += (size_t)EE * DD * FF * 2;        // 64 MB
    __bf16* H   = (__bf16*)q;  q += (size_t)EE * LIST_STRIDE * FF * 2; // 256 MB
    __bf16* O   = (__bf16*)q;                                        // 64 MB

    hipMemsetAsync(sums, 0, 128, stream);

    moe_gate_kernel<<<256, 256, 0, stream>>>(x, gw, e1v, e2v, g1v, g2v, sums, xb);
    moe_scan_kernel<<<16, 256, 0, stream>>>(e1v, e2v, g1v, g2v, rnd, sums,
                                            etok, p1v, p2v, cnt1, cnt2, imp1, imp2);
    moe_aux_kernel<<<1, 64, 0, stream>>>(sums, imp1, imp2, out + (size_t)TT * DD);

    transpose_bf16_kernel<<<dim3(DD / 64, FF / 32, EE), 256, 0, stream>>>(w1, w1T, DD, FF);
    transpose_bf16_kernel<<<dim3(FF / 64, DD / 32, EE), 256, 0, stream>>>(w2, w2T, FF, DD);

    moe_ffn1_mfma<<<8192, 256, 0, stream>>>(xb, w1T, b1, etok, cnt1, cnt2, H);
    moe_ffn2_mfma<<<2048, 256, 0, stream>>>(H, w2T, b2, cnt1, cnt2, O);
    moe_combine_kernel<<<TT, 256, 0, stream>>>(O, g1v, g2v, p1v, p2v, out);
}